// Round 2
// baseline (517.596 us; speedup 1.0000x reference)
//
#include <hip/hip_runtime.h>

// SelfAttention: B=8, S=2048, D=1024, fp32 in/out, bf16 MFMA with split-precision
// Q/K projections and fp32 score/softmax path.
// d_ws layout: scF fp32[32M] (128MB) | W3h[3M] W2l[2M] eh[16M] el[16M] qh[16M] kh[16M] v16[16M] (u16)
// vT reuses eh after projections. Total ~298MB.

#define B_SZ 8
#define SEQ  2048
#define DIM  1024
#define MROWS (B_SZ * SEQ)  // 16384

typedef unsigned short u16;
typedef short short8 __attribute__((ext_vector_type(8)));
typedef unsigned short u16x4 __attribute__((ext_vector_type(4)));
typedef float f32x4 __attribute__((ext_vector_type(4)));

__device__ __forceinline__ u16 f2bf(float x) {
  unsigned int u = __float_as_uint(x);
  return (u16)((u + 0x7fffu + ((u >> 16) & 1u)) >> 16);  // RNE
}
__device__ __forceinline__ float bf2f(u16 h) {
  return __uint_as_float(((unsigned int)h) << 16);
}

__device__ __forceinline__ void gload_lds16(const u16* g, u16* l) {
  __builtin_amdgcn_global_load_lds(
      (__attribute__((address_space(1))) void*)(g),
      (__attribute__((address_space(3))) void*)(l), 16, 0, 0);
}

__device__ __forceinline__ f32x4 mfma_bf16(short8 a, short8 b, f32x4 c) {
  asm("v_mfma_f32_16x16x32_bf16 %0, %1, %2, %0" : "+v"(c) : "v"(a), "v"(b));
  return c;
}

// ---- single-operand 128x128 GEMM core (as round 0)
__device__ __forceinline__ void gemm_core(const u16* A, const u16* Bt, int K,
                                          int lda, int ldb, f32x4 (&acc)[4][4],
                                          u16* sA, u16* sB) {
  const int tid = threadIdx.x;
  const int lane = tid & 63;
  const int wid = tid >> 6;
  const int wr = wid >> 1;
  const int wc = wid & 1;
  const int srow = tid >> 2;
  const int scol = (tid & 3) << 3;
  const u16* ga0 = A + (size_t)srow * lda + scol;
  const u16* ga1 = A + (size_t)(srow + 64) * lda + scol;
  const u16* gb0 = Bt + (size_t)srow * ldb + scol;
  const u16* gb1 = Bt + (size_t)(srow + 64) * ldb + scol;
  u16* la0 = sA + (wid << 9);
  u16* la1 = sA + 2048 + (wid << 9);
  u16* lb0 = sB + (wid << 9);
  u16* lb1 = sB + 2048 + (wid << 9);
  const u16* pa = sA + (size_t)((wr << 6) + (lane & 15)) * 32 + ((lane >> 4) << 3);
  const u16* pb = sB + (size_t)((wc << 6) + (lane & 15)) * 32 + ((lane >> 4) << 3);

  const int ksteps = K >> 5;
  for (int kt = 0; kt < ksteps; ++kt) {
    gload_lds16(ga0, la0);
    gload_lds16(ga1, la1);
    gload_lds16(gb0, lb0);
    gload_lds16(gb1, lb1);
    ga0 += 32; ga1 += 32; gb0 += 32; gb1 += 32;
    __syncthreads();
    short8 a[4], b[4];
#pragma unroll
    for (int i = 0; i < 4; ++i) a[i] = *(const short8*)(pa + (i << 9));
#pragma unroll
    for (int i = 0; i < 4; ++i) b[i] = *(const short8*)(pb + (i << 9));
#pragma unroll
    for (int mi = 0; mi < 4; ++mi)
#pragma unroll
      for (int ni = 0; ni < 4; ++ni)
        acc[mi][ni] = mfma_bf16(a[mi], b[ni], acc[mi][ni]);
    __syncthreads();
  }
  asm volatile("s_nop 7\n\ts_nop 7\n\ts_nop 7" ::);
}

// ---- 3-term split GEMM core: acc += Ah*Bh^T + Al*Bh^T + Ah*Bl^T
__device__ __forceinline__ void gemm_core3(const u16* Ah, const u16* Al,
                                           const u16* Bh, const u16* Bl, int K,
                                           int lda, int ldb, f32x4 (&acc)[4][4],
                                           u16* sAh, u16* sAl, u16* sBh, u16* sBl) {
  const int tid = threadIdx.x;
  const int lane = tid & 63;
  const int wid = tid >> 6;
  const int wr = wid >> 1;
  const int wc = wid & 1;
  const int srow = tid >> 2;
  const int scol = (tid & 3) << 3;
  const size_t goff0 = (size_t)srow * lda + scol;
  const size_t goff1 = (size_t)(srow + 64) * lda + scol;
  const size_t hoff0 = (size_t)srow * ldb + scol;
  const size_t hoff1 = (size_t)(srow + 64) * ldb + scol;
  const int lo0 = (wid << 9);
  const int lo1 = 2048 + (wid << 9);
  const int foa = ((wr << 6) + (lane & 15)) * 32 + ((lane >> 4) << 3);
  const int fob = ((wc << 6) + (lane & 15)) * 32 + ((lane >> 4) << 3);

  const int ksteps = K >> 5;
  for (int kt = 0; kt < ksteps; ++kt) {
    const size_t kk = (size_t)(kt << 5);
    gload_lds16(Ah + goff0 + kk, sAh + lo0);
    gload_lds16(Ah + goff1 + kk, sAh + lo1);
    gload_lds16(Al + goff0 + kk, sAl + lo0);
    gload_lds16(Al + goff1 + kk, sAl + lo1);
    gload_lds16(Bh + hoff0 + kk, sBh + lo0);
    gload_lds16(Bh + hoff1 + kk, sBh + lo1);
    gload_lds16(Bl + hoff0 + kk, sBl + lo0);
    gload_lds16(Bl + hoff1 + kk, sBl + lo1);
    __syncthreads();
    short8 ah[4], al[4], bh[4], bl[4];
#pragma unroll
    for (int i = 0; i < 4; ++i) {
      ah[i] = *(const short8*)(sAh + foa + (i << 9));
      al[i] = *(const short8*)(sAl + foa + (i << 9));
      bh[i] = *(const short8*)(sBh + fob + (i << 9));
      bl[i] = *(const short8*)(sBl + fob + (i << 9));
    }
#pragma unroll
    for (int mi = 0; mi < 4; ++mi)
#pragma unroll
      for (int ni = 0; ni < 4; ++ni) {
        acc[mi][ni] = mfma_bf16(ah[mi], bh[ni], acc[mi][ni]);
        acc[mi][ni] = mfma_bf16(al[mi], bh[ni], acc[mi][ni]);
        acc[mi][ni] = mfma_bf16(ah[mi], bl[ni], acc[mi][ni]);
      }
    __syncthreads();
  }
  asm volatile("s_nop 7\n\ts_nop 7\n\ts_nop 7" ::);
}

// ---- fp32 -> bf16 (hi only)
__global__ __launch_bounds__(256) void cvt_kernel(const float* __restrict__ in,
                                                  u16* __restrict__ out, int n4) {
  int i = blockIdx.x * 256 + threadIdx.x;
  if (i >= n4) return;
  float4 v = ((const float4*)in)[i];
  u16x4 o;
  o[0] = f2bf(v.x); o[1] = f2bf(v.y); o[2] = f2bf(v.z); o[3] = f2bf(v.w);
  ((u16x4*)out)[i] = o;
}

// ---- fp32 -> bf16 hi + bf16 residual lo
__global__ __launch_bounds__(256) void cvt_hilo_kernel(const float* __restrict__ in,
                                                       u16* __restrict__ oh,
                                                       u16* __restrict__ ol, int n4) {
  int i = blockIdx.x * 256 + threadIdx.x;
  if (i >= n4) return;
  float4 v = ((const float4*)in)[i];
  u16x4 h, l;
#pragma unroll
  for (int j = 0; j < 4; ++j) {
    float x = (j == 0) ? v.x : (j == 1) ? v.y : (j == 2) ? v.z : v.w;
    u16 hb = f2bf(x);
    h[j] = hb;
    l[j] = f2bf(x - bf2f(hb));
  }
  ((u16x4*)oh)[i] = h;
  ((u16x4*)ol)[i] = l;
}

// ---- Q/K projections, 3-term split: out = bf16( (eh+el)@(Wh+Wl)^T + b ) (z: 0=q, 1=k)
__global__ __launch_bounds__(256) void proj_qk_kernel(const u16* __restrict__ eh,
                                                      const u16* __restrict__ el,
                                                      const u16* __restrict__ W3h,
                                                      const u16* __restrict__ W2l,
                                                      const float* __restrict__ bq,
                                                      const float* __restrict__ bk,
                                                      u16* __restrict__ qh,
                                                      u16* __restrict__ kh) {
  __shared__ __align__(16) u16 sAh[128 * 32];
  __shared__ __align__(16) u16 sAl[128 * 32];
  __shared__ __align__(16) u16 sBh[128 * 32];
  __shared__ __align__(16) u16 sBl[128 * 32];
  const int m0 = blockIdx.x * 128, n0 = blockIdx.y * 128, z = blockIdx.z;
  const u16* Ah = eh + (size_t)m0 * DIM;
  const u16* Al = el + (size_t)m0 * DIM;
  const u16* Bh = W3h + (size_t)z * DIM * DIM + (size_t)n0 * DIM;
  const u16* Bl = W2l + (size_t)z * DIM * DIM + (size_t)n0 * DIM;
  const float* bias = z ? bk : bq;
  u16* out = z ? kh : qh;
  f32x4 acc[4][4] = {};
  gemm_core3(Ah, Al, Bh, Bl, DIM, DIM, DIM, acc, sAh, sAl, sBh, sBl);
  const int lane = threadIdx.x & 63, wid = threadIdx.x >> 6;
  const int wr = wid >> 1, wc = wid & 1;
#pragma unroll
  for (int mi = 0; mi < 4; ++mi)
#pragma unroll
    for (int ni = 0; ni < 4; ++ni)
#pragma unroll
      for (int j = 0; j < 4; ++j) {
        int row = m0 + (wr << 6) + mi * 16 + ((lane >> 4) << 2) + j;
        int col = n0 + (wc << 6) + ni * 16 + (lane & 15);
        out[(size_t)row * DIM + col] = f2bf(acc[mi][ni][j] + bias[col]);
      }
}

// ---- V projection (single-term)
__global__ __launch_bounds__(256) void proj_v_kernel(const u16* __restrict__ eh,
                                                     const u16* __restrict__ Wvh,
                                                     const float* __restrict__ bv,
                                                     u16* __restrict__ v16) {
  __shared__ __align__(16) u16 sA[128 * 32];
  __shared__ __align__(16) u16 sB[128 * 32];
  const int m0 = blockIdx.x * 128, n0 = blockIdx.y * 128;
  const u16* A = eh + (size_t)m0 * DIM;
  const u16* Bt = Wvh + (size_t)n0 * DIM;
  f32x4 acc[4][4] = {};
  gemm_core(A, Bt, DIM, DIM, DIM, acc, sA, sB);
  const int lane = threadIdx.x & 63, wid = threadIdx.x >> 6;
  const int wr = wid >> 1, wc = wid & 1;
#pragma unroll
  for (int mi = 0; mi < 4; ++mi)
#pragma unroll
    for (int ni = 0; ni < 4; ++ni)
#pragma unroll
      for (int j = 0; j < 4; ++j) {
        int row = m0 + (wr << 6) + mi * 16 + ((lane >> 4) << 2) + j;
        int col = n0 + (wc << 6) + ni * 16 + (lane & 15);
        v16[(size_t)row * DIM + col] = f2bf(acc[mi][ni][j] + bv[col]);
      }
}

// ---- v[b][k][d] -> vT[b][d][k]
__global__ __launch_bounds__(256) void transpose_kernel(const u16* __restrict__ v,
                                                        u16* __restrict__ vt) {
  __shared__ u16 t[64][68];
  const int b = blockIdx.z;
  const int k0 = blockIdx.x * 64;
  const int d0 = blockIdx.y * 64;
  const int tid = threadIdx.x;
  const int r = tid >> 4;
  const int c4 = (tid & 15) << 2;
  const u16* src = v + ((size_t)b * SEQ + k0) * DIM + d0;
#pragma unroll
  for (int i = 0; i < 4; ++i) {
    u16x4 x = *(const u16x4*)(src + (size_t)(r + 16 * i) * DIM + c4);
    t[r + 16 * i][c4 + 0] = x[0];
    t[r + 16 * i][c4 + 1] = x[1];
    t[r + 16 * i][c4 + 2] = x[2];
    t[r + 16 * i][c4 + 3] = x[3];
  }
  __syncthreads();
  u16* dst = vt + ((size_t)b * DIM + d0) * SEQ + k0;
#pragma unroll
  for (int i = 0; i < 4; ++i) {
    int dr = r + 16 * i;
    u16x4 y;
    y[0] = t[c4 + 0][dr];
    y[1] = t[c4 + 1][dr];
    y[2] = t[c4 + 2][dr];
    y[3] = t[c4 + 3][dr];
    *(u16x4*)(dst + (size_t)dr * SEQ + c4) = y;
  }
}

// ---- scores (fp32 out): scF = (q.k + mask) / 32
__global__ __launch_bounds__(256) void scores_kernel(const u16* __restrict__ qh,
                                                     const u16* __restrict__ kh,
                                                     const float* __restrict__ mask,
                                                     float* __restrict__ scF) {
  __shared__ __align__(16) u16 sA[128 * 32];
  __shared__ __align__(16) u16 sB[128 * 32];
  const int m0 = blockIdx.x * 128, n0 = blockIdx.y * 128, b = blockIdx.z;
  const u16* A = qh + ((size_t)b * SEQ + m0) * DIM;
  const u16* Bt = kh + ((size_t)b * SEQ + n0) * DIM;
  f32x4 acc[4][4] = {};
  gemm_core(A, Bt, DIM, DIM, DIM, acc, sA, sB);
  const int lane = threadIdx.x & 63, wid = threadIdx.x >> 6;
  const int wr = wid >> 1, wc = wid & 1;
#pragma unroll
  for (int mi = 0; mi < 4; ++mi)
#pragma unroll
    for (int ni = 0; ni < 4; ++ni)
#pragma unroll
      for (int j = 0; j < 4; ++j) {
        int row = m0 + (wr << 6) + mi * 16 + ((lane >> 4) << 2) + j;
        int col = n0 + (wc << 6) + ni * 16 + (lane & 15);
        size_t idx = ((size_t)b * SEQ + row) * SEQ + col;
        scF[idx] = (acc[mi][ni][j] + mask[idx]) * 0.03125f;
      }
}

// ---- fp32 row softmax; writes bf16 probs in place into row-local first half
__global__ __launch_bounds__(256) void softmax_kernel(float* __restrict__ scF) {
  __shared__ float red[8];
  const size_t row = blockIdx.x;
  float* rowp = scF + row * SEQ;
  const int tid = threadIdx.x;
  float4 v0 = ((const float4*)rowp)[2 * tid];
  float4 v1 = ((const float4*)rowp)[2 * tid + 1];
  float f[8] = {v0.x, v0.y, v0.z, v0.w, v1.x, v1.y, v1.z, v1.w};
  float mx = f[0];
#pragma unroll
  for (int j = 1; j < 8; ++j) mx = fmaxf(mx, f[j]);
#pragma unroll
  for (int off = 1; off < 64; off <<= 1) mx = fmaxf(mx, __shfl_xor(mx, off));
  const int wid = tid >> 6, lane = tid & 63;
  if (lane == 0) red[wid] = mx;
  __syncthreads();
  mx = fmaxf(fmaxf(red[0], red[1]), fmaxf(red[2], red[3]));
  float e[8];
  float s = 0.f;
#pragma unroll
  for (int j = 0; j < 8; ++j) {
    e[j] = __expf(f[j] - mx);
    s += e[j];
  }
#pragma unroll
  for (int off = 1; off < 64; off <<= 1) s += __shfl_xor(s, off);
  if (lane == 0) red[4 + wid] = s;
  __syncthreads();
  s = (red[4] + red[5]) + (red[6] + red[7]);
  const float inv = 1.f / s;
  short8 o;
#pragma unroll
  for (int j = 0; j < 8; ++j) o[j] = (short)f2bf(e[j] * inv);
  // all reads done before the last __syncthreads above -> safe to overwrite
  *(short8*)((u16*)rowp + tid * 8) = o;
}

// ---- PV: out = probs @ v ; probs live at row stride 4096 u16 inside scF
__global__ __launch_bounds__(256) void pv_kernel(const u16* __restrict__ pr,
                                                 const u16* __restrict__ vt,
                                                 float* __restrict__ out) {
  __shared__ __align__(16) u16 sA[128 * 32];
  __shared__ __align__(16) u16 sB[128 * 32];
  const int m0 = blockIdx.x * 128, n0 = blockIdx.y * 128, b = blockIdx.z;
  const u16* A = pr + ((size_t)b * SEQ + m0) * (2 * SEQ);
  const u16* Bt = vt + ((size_t)b * DIM + n0) * SEQ;
  f32x4 acc[4][4] = {};
  gemm_core(A, Bt, SEQ, 2 * SEQ, SEQ, acc, sA, sB);
  const int lane = threadIdx.x & 63, wid = threadIdx.x >> 6;
  const int wr = wid >> 1, wc = wid & 1;
#pragma unroll
  for (int mi = 0; mi < 4; ++mi)
#pragma unroll
    for (int ni = 0; ni < 4; ++ni)
#pragma unroll
      for (int j = 0; j < 4; ++j) {
        int row = m0 + (wr << 6) + mi * 16 + ((lane >> 4) << 2) + j;
        int col = n0 + (wc << 6) + ni * 16 + (lane & 15);
        out[((size_t)b * SEQ + row) * DIM + col] = acc[mi][ni][j];
      }
}

extern "C" void kernel_launch(void* const* d_in, const int* in_sizes, int n_in,
                              void* d_out, int out_size, void* d_ws, size_t ws_size,
                              hipStream_t stream) {
  const float* emb  = (const float*)d_in[0];
  const float* mask = (const float*)d_in[1];
  const float* Wq   = (const float*)d_in[2];
  const float* bq   = (const float*)d_in[3];
  const float* Wk   = (const float*)d_in[4];
  const float* bk   = (const float*)d_in[5];
  const float* Wv   = (const float*)d_in[6];
  const float* bv   = (const float*)d_in[7];
  float* out = (float*)d_out;

  const size_t M1 = 1024 * 1024;
  float* scF = (float*)d_ws;                        // 32M floats (128MB)
  u16* W3h = (u16*)d_ws + 64 * M1;                  // 3M u16
  u16* W2l = W3h + 3 * M1;                          // 2M
  u16* eh  = W2l + 2 * M1;                          // 16M
  u16* el  = eh + 16 * M1;                          // 16M
  u16* qh  = el + 16 * M1;                          // 16M
  u16* kh  = qh + 16 * M1;                          // 16M
  u16* v16 = kh + 16 * M1;                          // 16M
  u16* vT  = eh;  // eh dead after projections

  cvt_hilo_kernel<<<16384, 256, 0, stream>>>(emb, eh, el, (int)(4 * M1));
  cvt_hilo_kernel<<<1024, 256, 0, stream>>>(Wq, W3h, W2l, (int)(M1 / 4));
  cvt_hilo_kernel<<<1024, 256, 0, stream>>>(Wk, W3h + M1, W2l + M1, (int)(M1 / 4));
  cvt_kernel<<<1024, 256, 0, stream>>>(Wv, W3h + 2 * M1, (int)(M1 / 4));

  proj_qk_kernel<<<dim3(MROWS / 128, DIM / 128, 2), 256, 0, stream>>>(
      eh, el, W3h, W2l, bq, bk, qh, kh);
  proj_v_kernel<<<dim3(MROWS / 128, DIM / 128), 256, 0, stream>>>(
      eh, W3h + 2 * M1, bv, v16);

  transpose_kernel<<<dim3(SEQ / 64, DIM / 64, B_SZ), 256, 0, stream>>>(v16, vT);

  scores_kernel<<<dim3(SEQ / 128, SEQ / 128, B_SZ), 256, 0, stream>>>(qh, kh, mask, scF);
  softmax_kernel<<<MROWS, 256, 0, stream>>>(scF);
  pv_kernel<<<dim3(SEQ / 128, DIM / 128, B_SZ), 256, 0, stream>>>((const u16*)scF, vT, out);
}

// Round 3
// 402.826 us; speedup vs baseline: 1.2849x; 1.2849x over previous
//
#include <hip/hip_runtime.h>

// SelfAttention: B=8, S=2048, D=1024, fp32 in/out.
// GEMMs on a 256x256-tile, 8-wave, BK=64 double-buffered MFMA core with
// swizzled LDS (pre-swizzled global staging), counted vmcnt, setprio.
// Q/K precision: stacked-K [emb_hi | emb_lo] @ [Wh | Wh] = (eh+el)*Wh (fp32-grade emb).
// Scores/softmax in fp32; probs bf16 in-place; PV bf16 MFMA.
// d_ws (u16 units): scF fp32[32M]=64M | A2[32M] | Bq[2M] Bk[2M] Bv[1M] | q16[16M] k16[16M] v16[16M]
//   vT reuses A2 after projections. Total 149M u16 = 298MB.

#define B_SZ 8
#define SEQ  2048
#define DIM  1024
#define MROWS (B_SZ * SEQ)  // 16384

typedef unsigned short u16;
typedef short short8 __attribute__((ext_vector_type(8)));
typedef unsigned short u16x4 __attribute__((ext_vector_type(4)));
typedef float f32x4 __attribute__((ext_vector_type(4)));

__device__ __forceinline__ u16 f2bf(float x) {
  unsigned int u = __float_as_uint(x);
  return (u16)((u + 0x7fffu + ((u >> 16) & 1u)) >> 16);  // RNE
}
__device__ __forceinline__ float bf2f(u16 h) {
  return __uint_as_float(((unsigned int)h) << 16);
}

__device__ __forceinline__ void gload_lds16(const u16* g, u16* l) {
  __builtin_amdgcn_global_load_lds(
      (__attribute__((address_space(1))) void*)(g),
      (__attribute__((address_space(3))) void*)(l), 16, 0, 0);
}

__device__ __forceinline__ f32x4 mfma_bf16(short8 a, short8 b, f32x4 c) {
  asm("v_mfma_f32_16x16x32_bf16 %0, %1, %2, %0" : "+v"(c) : "v"(a), "v"(b));
  return c;
}

// ================= 256x256 8-wave GEMM core =================
// C(256x256) += A(256xK) * Bt(256xK)^T. 512 threads = 8 waves (2M x 4N),
// per-wave 128x64 = 8x4 16x16 frags. BK=64, double-buffered LDS (128KB).
// LDS layout per operand tile [256][64] bf16: 16x32-subtiled, byte-swizzled
// (bit5 ^= bit9 within each 1KB subtile), realized by pre-swizzled global src.
// Issue order per tile: B0,B1,B2,B3,A0,A1,A2,A3 (8KB each).
// Waits: tile entry vmcnt(1) [A3 may fly; consumed ph2/3]; mid-tile vmcnt(4).
__device__ __forceinline__ void gemm256_core(const u16* __restrict__ Ag,
                                             const u16* __restrict__ Bg,
                                             int NT, size_t lda, size_t ldb,
                                             u16* sm, f32x4 (&acc)[8][4]) {
  const int tid = threadIdx.x;
  const int lane = tid & 63;
  const int wid = tid >> 6;   // 0..7
  const int wm = wid >> 2;    // 0..1
  const int wn = wid & 3;     // 0..3
  const int wm8 = wm << 3;
  const int wn4 = wn << 2;

  u16* sA = sm;            // [2][16384] u16 (32KB per buf)
  u16* sB = sm + 32768;

  // staging decode: thread covers LDS bytes j*8192 + tid*16 of each operand tile.
  // b' = lane*16 ; b = b' ^ (bit9(b')<<5) ; r_in_sub = b>>6 ; c_in_sub = (b&63)>>1
  const int bb = (lane << 4) ^ (((lane >> 5) & 1) << 5);
  const int rins = bb >> 6;
  const int cins = (bb & 63) >> 1;
  const int s0 = wid, s1 = 8 + wid, s2 = 16 + wid, s3 = 24 + wid;
  const size_t aoff0 = (size_t)((s0 >> 1) * 16 + rins) * lda + ((s0 & 1) * 32 + cins);
  const size_t aoff1 = (size_t)((s1 >> 1) * 16 + rins) * lda + ((s1 & 1) * 32 + cins);
  const size_t aoff2 = (size_t)((s2 >> 1) * 16 + rins) * lda + ((s2 & 1) * 32 + cins);
  const size_t aoff3 = (size_t)((s3 >> 1) * 16 + rins) * lda + ((s3 & 1) * 32 + cins);
  const size_t boff0 = (size_t)((s0 >> 1) * 16 + rins) * ldb + ((s0 & 1) * 32 + cins);
  const size_t boff1 = (size_t)((s1 >> 1) * 16 + rins) * ldb + ((s1 & 1) * 32 + cins);
  const size_t boff2 = (size_t)((s2 >> 1) * 16 + rins) * ldb + ((s2 & 1) * 32 + cins);
  const size_t boff3 = (size_t)((s3 >> 1) * 16 + rins) * ldb + ((s3 & 1) * 32 + cins);
  const int wid512 = wid << 9;  // wid*512 u16 = wid*1024 bytes

  // fragment read offset (u16): lane_off = (l&15)*64 + (l>>4)*16 bytes, swizzled
  const int lof = ((lane & 15) << 6) + ((lane >> 4) << 4);
  const int loe = (lof ^ (((lane >> 3) & 1) << 5)) >> 1;

#define ISSUE_A(j, nb, kt) \
  gload_lds16(Ag + aoff##j + (size_t)(kt) * 64, sA + (nb) * 16384 + (j) * 4096 + wid512)
#define ISSUE_B(j, nb, kt) \
  gload_lds16(Bg + boff##j + (size_t)(kt) * 64, sB + (nb) * 16384 + (j) * 4096 + wid512)

  // prologue: stage tile 0 into buf 0
  ISSUE_B(0, 0, 0); ISSUE_B(1, 0, 0); ISSUE_B(2, 0, 0); ISSUE_B(3, 0, 0);
  ISSUE_A(0, 0, 0); ISSUE_A(1, 0, 0); ISSUE_A(2, 0, 0); ISSUE_A(3, 0, 0);

  int buf = 0;
  for (int kt = 0; kt < NT; ++kt) {
    const int nk = kt + 1;
    const bool pre = nk < NT;
    const int nb = buf ^ 1;
    asm volatile("s_waitcnt vmcnt(1)" ::: "memory");
    __builtin_amdgcn_s_barrier();
    asm volatile("" ::: "memory");
    const u16* bufA = sA + buf * 16384;
    const u16* bufB = sB + buf * 16384;
    short8 bf[4][2];
#pragma unroll
    for (int n = 0; n < 4; ++n) {
      bf[n][0] = *(const short8*)(bufB + (wn4 + n) * 1024 + loe);
      bf[n][1] = *(const short8*)(bufB + (wn4 + n) * 1024 + 512 + loe);
    }
    // ---- phase 0 (m0,m1)
    {
      short8 af[2][2];
#pragma unroll
      for (int m = 0; m < 2; ++m) {
        af[m][0] = *(const short8*)(bufA + (wm8 + m) * 1024 + loe);
        af[m][1] = *(const short8*)(bufA + (wm8 + m) * 1024 + 512 + loe);
      }
      if (pre) { ISSUE_B(0, nb, nk); ISSUE_B(1, nb, nk); }
      __builtin_amdgcn_s_setprio(1);
#pragma unroll
      for (int m = 0; m < 2; ++m)
#pragma unroll
        for (int n = 0; n < 4; ++n) {
          acc[m][n] = mfma_bf16(af[m][0], bf[n][0], acc[m][n]);
          acc[m][n] = mfma_bf16(af[m][1], bf[n][1], acc[m][n]);
        }
      __builtin_amdgcn_s_setprio(0);
    }
    // ---- phase 1 (m2,m3)
    {
      short8 af[2][2];
#pragma unroll
      for (int m = 0; m < 2; ++m) {
        af[m][0] = *(const short8*)(bufA + (wm8 + 2 + m) * 1024 + loe);
        af[m][1] = *(const short8*)(bufA + (wm8 + 2 + m) * 1024 + 512 + loe);
      }
      if (pre) { ISSUE_B(2, nb, nk); ISSUE_B(3, nb, nk); }
      __builtin_amdgcn_s_setprio(1);
#pragma unroll
      for (int m = 0; m < 2; ++m)
#pragma unroll
        for (int n = 0; n < 4; ++n) {
          acc[2 + m][n] = mfma_bf16(af[m][0], bf[n][0], acc[2 + m][n]);
          acc[2 + m][n] = mfma_bf16(af[m][1], bf[n][1], acc[2 + m][n]);
        }
      __builtin_amdgcn_s_setprio(0);
    }
    // ---- mid-tile: A3 of current tile must land (A-half-2 consumed by wm=1)
    if (pre) {
      asm volatile("s_waitcnt vmcnt(4)" ::: "memory");
    } else {
      asm volatile("s_waitcnt vmcnt(0)" ::: "memory");
    }
    __builtin_amdgcn_s_barrier();
    asm volatile("" ::: "memory");
    // ---- phase 2 (m4,m5)
    {
      short8 af[2][2];
#pragma unroll
      for (int m = 0; m < 2; ++m) {
        af[m][0] = *(const short8*)(bufA + (wm8 + 4 + m) * 1024 + loe);
        af[m][1] = *(const short8*)(bufA + (wm8 + 4 + m) * 1024 + 512 + loe);
      }
      if (pre) { ISSUE_A(0, nb, nk); ISSUE_A(1, nb, nk); }
      __builtin_amdgcn_s_setprio(1);
#pragma unroll
      for (int m = 0; m < 2; ++m)
#pragma unroll
        for (int n = 0; n < 4; ++n) {
          acc[4 + m][n] = mfma_bf16(af[m][0], bf[n][0], acc[4 + m][n]);
          acc[4 + m][n] = mfma_bf16(af[m][1], bf[n][1], acc[4 + m][n]);
        }
      __builtin_amdgcn_s_setprio(0);
    }
    // ---- phase 3 (m6,m7)
    {
      short8 af[2][2];
#pragma unroll
      for (int m = 0; m < 2; ++m) {
        af[m][0] = *(const short8*)(bufA + (wm8 + 6 + m) * 1024 + loe);
        af[m][1] = *(const short8*)(bufA + (wm8 + 6 + m) * 1024 + 512 + loe);
      }
      if (pre) { ISSUE_A(2, nb, nk); ISSUE_A(3, nb, nk); }
      __builtin_amdgcn_s_setprio(1);
#pragma unroll
      for (int m = 0; m < 2; ++m)
#pragma unroll
        for (int n = 0; n < 4; ++n) {
          acc[6 + m][n] = mfma_bf16(af[m][0], bf[n][0], acc[6 + m][n]);
          acc[6 + m][n] = mfma_bf16(af[m][1], bf[n][1], acc[6 + m][n]);
        }
      __builtin_amdgcn_s_setprio(0);
    }
    buf ^= 1;
  }
  asm volatile("s_nop 7\n\ts_nop 7\n\ts_nop 7" ::);  // MFMA->VALU hazard guard
#undef ISSUE_A
#undef ISSUE_B
}

// ---- emb fp32 -> A2 = [hi | lo] stacked rows [16384][2048]
__global__ __launch_bounds__(256) void cvt_emb2_kernel(const float* __restrict__ in,
                                                       u16* __restrict__ A2) {
  int i = blockIdx.x * 256 + threadIdx.x;  // over 4M float4
  float4 v = ((const float4*)in)[i];
  int r = i >> 8;
  int c = (i & 255) << 2;
  u16x4 h, l;
#pragma unroll
  for (int j = 0; j < 4; ++j) {
    float x = (j == 0) ? v.x : (j == 1) ? v.y : (j == 2) ? v.z : v.w;
    u16 hb = f2bf(x);
    h[j] = hb;
    l[j] = f2bf(x - bf2f(hb));
  }
  *(u16x4*)(A2 + (size_t)r * 2048 + c) = h;
  *(u16x4*)(A2 + (size_t)r * 2048 + 1024 + c) = l;
}

// ---- W fp32 -> B = [Wh | Wh] stacked rows [1024][2048]
__global__ __launch_bounds__(256) void cvt_wstack_kernel(const float* __restrict__ in,
                                                         u16* __restrict__ B) {
  int i = blockIdx.x * 256 + threadIdx.x;  // over 256K float4
  float4 v = ((const float4*)in)[i];
  int r = i >> 8;
  int c = (i & 255) << 2;
  u16x4 h;
  h[0] = f2bf(v.x); h[1] = f2bf(v.y); h[2] = f2bf(v.z); h[3] = f2bf(v.w);
  *(u16x4*)(B + (size_t)r * 2048 + c) = h;
  *(u16x4*)(B + (size_t)r * 2048 + 1024 + c) = h;
}

// ---- Wv fp32 -> bf16 [1024][1024]
__global__ __launch_bounds__(256) void cvt_w_kernel(const float* __restrict__ in,
                                                    u16* __restrict__ B) {
  int i = blockIdx.x * 256 + threadIdx.x;
  float4 v = ((const float4*)in)[i];
  int r = i >> 8;
  int c = (i & 255) << 2;
  u16x4 h;
  h[0] = f2bf(v.x); h[1] = f2bf(v.y); h[2] = f2bf(v.z); h[3] = f2bf(v.w);
  *(u16x4*)(B + (size_t)r * 1024 + c) = h;
}

// ---- fused projections: z=0 q (K=2048 stacked), z=1 k (stacked), z=2 v (K=1024)
__global__ __launch_bounds__(512) void proj256_kernel(const u16* __restrict__ A2,
                                                      const u16* __restrict__ Bq,
                                                      const u16* __restrict__ Bk,
                                                      const u16* __restrict__ Bv,
                                                      const float* __restrict__ bq,
                                                      const float* __restrict__ bk,
                                                      const float* __restrict__ bv,
                                                      u16* __restrict__ q16,
                                                      u16* __restrict__ k16,
                                                      u16* __restrict__ v16) {
  __shared__ __align__(16) u16 sm[65536];  // 128KB
  const int z = blockIdx.z;
  const int m0 = blockIdx.y * 256, n0 = blockIdx.x * 256;
  const u16* Bg = (z == 0) ? Bq : (z == 1) ? Bk : Bv;
  const float* bias = (z == 0) ? bq : (z == 1) ? bk : bv;
  u16* dst = (z == 0) ? q16 : (z == 1) ? k16 : v16;
  const size_t ldb = (z == 2) ? 1024 : 2048;
  const int NT = (z == 2) ? 16 : 32;
  f32x4 acc[8][4] = {};
  gemm256_core(A2 + (size_t)m0 * 2048, Bg + (size_t)n0 * ldb, NT, 2048, ldb, sm, acc);
  const int lane = threadIdx.x & 63, wid = threadIdx.x >> 6;
  const int rb = m0 + ((wid >> 2) << 7) + ((lane >> 4) << 2);
  const int cb = n0 + ((wid & 3) << 6) + (lane & 15);
#pragma unroll
  for (int m = 0; m < 8; ++m)
#pragma unroll
    for (int n = 0; n < 4; ++n)
#pragma unroll
      for (int j = 0; j < 4; ++j) {
        int row = rb + m * 16 + j;
        int col = cb + n * 16;
        dst[(size_t)row * DIM + col] = f2bf(acc[m][n][j] + bias[col]);
      }
}

// ---- scores: scF = (q.k^T + mask) / 32  (fp32)
__global__ __launch_bounds__(512) void scores256_kernel(const u16* __restrict__ q16,
                                                        const u16* __restrict__ k16,
                                                        const float* __restrict__ mask,
                                                        float* __restrict__ scF) {
  __shared__ __align__(16) u16 sm[65536];
  const int b = blockIdx.z;
  const int m0 = blockIdx.y * 256, n0 = blockIdx.x * 256;
  f32x4 acc[8][4] = {};
  gemm256_core(q16 + ((size_t)b * SEQ + m0) * DIM, k16 + ((size_t)b * SEQ + n0) * DIM,
               16, DIM, DIM, sm, acc);
  const int lane = threadIdx.x & 63, wid = threadIdx.x >> 6;
  const int rb = m0 + ((wid >> 2) << 7) + ((lane >> 4) << 2);
  const int cb = n0 + ((wid & 3) << 6) + (lane & 15);
#pragma unroll
  for (int m = 0; m < 8; ++m)
#pragma unroll
    for (int n = 0; n < 4; ++n)
#pragma unroll
      for (int j = 0; j < 4; ++j) {
        size_t idx = ((size_t)b * SEQ + rb + m * 16 + j) * SEQ + (cb + n * 16);
        scF[idx] = (acc[m][n][j] + mask[idx]) * 0.03125f;
      }
}

// ---- PV: out = probs @ v  (probs bf16 at row stride 4096 u16 inside scF)
__global__ __launch_bounds__(512) void pv256_kernel(const u16* __restrict__ pr,
                                                    const u16* __restrict__ vt,
                                                    float* __restrict__ out) {
  __shared__ __align__(16) u16 sm[65536];
  const int b = blockIdx.z;
  const int m0 = blockIdx.y * 256, n0 = blockIdx.x * 256;
  f32x4 acc[8][4] = {};
  gemm256_core(pr + ((size_t)b * SEQ + m0) * (2 * SEQ), vt + ((size_t)b * DIM + n0) * SEQ,
               32, 2 * SEQ, SEQ, sm, acc);
  const int lane = threadIdx.x & 63, wid = threadIdx.x >> 6;
  const int rb = m0 + ((wid >> 2) << 7) + ((lane >> 4) << 2);
  const int cb = n0 + ((wid & 3) << 6) + (lane & 15);
#pragma unroll
  for (int m = 0; m < 8; ++m)
#pragma unroll
    for (int n = 0; n < 4; ++n)
#pragma unroll
      for (int j = 0; j < 4; ++j)
        out[((size_t)b * SEQ + rb + m * 16 + j) * DIM + (cb + n * 16)] = acc[m][n][j];
}

// ---- v[b][k][d] -> vT[b][d][k]
__global__ __launch_bounds__(256) void transpose_kernel(const u16* __restrict__ v,
                                                        u16* __restrict__ vt) {
  __shared__ u16 t[64][68];
  const int b = blockIdx.z;
  const int k0 = blockIdx.x * 64;
  const int d0 = blockIdx.y * 64;
  const int tid = threadIdx.x;
  const int r = tid >> 4;
  const int c4 = (tid & 15) << 2;
  const u16* src = v + ((size_t)b * SEQ + k0) * DIM + d0;
#pragma unroll
  for (int i = 0; i < 4; ++i) {
    u16x4 x = *(const u16x4*)(src + (size_t)(r + 16 * i) * DIM + c4);
    t[r + 16 * i][c4 + 0] = x[0];
    t[r + 16 * i][c4 + 1] = x[1];
    t[r + 16 * i][c4 + 2] = x[2];
    t[r + 16 * i][c4 + 3] = x[3];
  }
  __syncthreads();
  u16* dst = vt + ((size_t)b * DIM + d0) * SEQ + k0;
#pragma unroll
  for (int i = 0; i < 4; ++i) {
    int dr = r + 16 * i;
    u16x4 y;
    y[0] = t[c4 + 0][dr];
    y[1] = t[c4 + 1][dr];
    y[2] = t[c4 + 2][dr];
    y[3] = t[c4 + 3][dr];
    *(u16x4*)(dst + (size_t)dr * SEQ + c4) = y;
  }
}

// ---- fp32 row softmax; writes bf16 probs in place into row-local first half
__global__ __launch_bounds__(256) void softmax_kernel(float* __restrict__ scF) {
  __shared__ float red[8];
  const size_t row = blockIdx.x;
  float* rowp = scF + row * SEQ;
  const int tid = threadIdx.x;
  float4 v0 = ((const float4*)rowp)[2 * tid];
  float4 v1 = ((const float4*)rowp)[2 * tid + 1];
  float f[8] = {v0.x, v0.y, v0.z, v0.w, v1.x, v1.y, v1.z, v1.w};
  float mx = f[0];
#pragma unroll
  for (int j = 1; j < 8; ++j) mx = fmaxf(mx, f[j]);
#pragma unroll
  for (int off = 1; off < 64; off <<= 1) mx = fmaxf(mx, __shfl_xor(mx, off));
  const int wid = tid >> 6, lane = tid & 63;
  if (lane == 0) red[wid] = mx;
  __syncthreads();
  mx = fmaxf(fmaxf(red[0], red[1]), fmaxf(red[2], red[3]));
  float e[8];
  float s = 0.f;
#pragma unroll
  for (int j = 0; j < 8; ++j) {
    e[j] = __expf(f[j] - mx);
    s += e[j];
  }
#pragma unroll
  for (int off = 1; off < 64; off <<= 1) s += __shfl_xor(s, off);
  if (lane == 0) red[4 + wid] = s;
  __syncthreads();
  s = (red[4] + red[5]) + (red[6] + red[7]);
  const float inv = 1.f / s;
  short8 o;
#pragma unroll
  for (int j = 0; j < 8; ++j) o[j] = (short)f2bf(e[j] * inv);
  *(short8*)((u16*)rowp + tid * 8) = o;
}

extern "C" void kernel_launch(void* const* d_in, const int* in_sizes, int n_in,
                              void* d_out, int out_size, void* d_ws, size_t ws_size,
                              hipStream_t stream) {
  const float* emb  = (const float*)d_in[0];
  const float* mask = (const float*)d_in[1];
  const float* Wq   = (const float*)d_in[2];
  const float* bq   = (const float*)d_in[3];
  const float* Wk   = (const float*)d_in[4];
  const float* bk   = (const float*)d_in[5];
  const float* Wv   = (const float*)d_in[6];
  const float* bv   = (const float*)d_in[7];
  float* out = (float*)d_out;

  const size_t M1 = 1024 * 1024;
  float* scF = (float*)d_ws;                 // 32M fp32 (128MB)
  u16* A2  = (u16*)d_ws + 64 * M1;           // 32M u16: [emb_hi | emb_lo]
  u16* Bq  = A2 + 32 * M1;                   // 2M
  u16* Bk  = Bq + 2 * M1;                    // 2M
  u16* Bv  = Bk + 2 * M1;                    // 1M
  u16* q16 = Bv + 1 * M1;                    // 16M
  u16* k16 = q16 + 16 * M1;                  // 16M
  u16* v16 = k16 + 16 * M1;                  // 16M  (ends at 149M u16 = 298MB)
  u16* vT  = A2;  // A2 dead after projections

  cvt_emb2_kernel<<<16384, 256, 0, stream>>>(emb, A2);
  cvt_wstack_kernel<<<1024, 256, 0, stream>>>(Wq, Bq);
  cvt_wstack_kernel<<<1024, 256, 0, stream>>>(Wk, Bk);
  cvt_w_kernel<<<1024, 256, 0, stream>>>(Wv, Bv);

  proj256_kernel<<<dim3(DIM / 256, MROWS / 256, 3), 512, 0, stream>>>(
      A2, Bq, Bk, Bv, bq, bk, bv, q16, k16, v16);

  transpose_kernel<<<dim3(SEQ / 64, DIM / 64, B_SZ), 256, 0, stream>>>(v16, vT);

  scores256_kernel<<<dim3(SEQ / 256, SEQ / 256, B_SZ), 512, 0, stream>>>(q16, k16, mask, scF);
  softmax_kernel<<<MROWS, 256, 0, stream>>>(scF);
  pv256_kernel<<<dim3(DIM / 256, SEQ / 256, B_SZ), 512, 0, stream>>>((const u16*)scF, vT, out);
}

// Round 4
// 397.608 us; speedup vs baseline: 1.3018x; 1.0131x over previous
//
#include <hip/hip_runtime.h>

// SelfAttention: B=8, S=2048, D=1024, fp32 in/out.
// GEMMs on a 256x256-tile, 8-wave, BK=64 double-buffered MFMA core with
// swizzled LDS (pre-swizzled global staging), counted vmcnt, setprio,
// XCD-chunked block swizzle (T1). V is projected directly transposed
// (vT = Wv @ emb^T) inside the fused projection kernel.
// Q/K precision: stacked-K [emb_hi | emb_lo] @ [Wh | Wh] = (eh+el)*Wh.
// Scores/softmax in fp32; probs bf16 in-place; PV bf16 MFMA.
// d_ws (u16 units): scF fp32[32M]=64M | A2[32M] | Bq[2M] Bk[2M] Bv[1M] |
//   q16[16M] k16[16M] vT[16M]. Total 149M u16 = 298MB.

#define B_SZ 8
#define SEQ  2048
#define DIM  1024
#define MROWS (B_SZ * SEQ)  // 16384

typedef unsigned short u16;
typedef short short8 __attribute__((ext_vector_type(8)));
typedef unsigned short u16x4 __attribute__((ext_vector_type(4)));
typedef float f32x4 __attribute__((ext_vector_type(4)));

__device__ __forceinline__ u16 f2bf(float x) {
  unsigned int u = __float_as_uint(x);
  return (u16)((u + 0x7fffu + ((u >> 16) & 1u)) >> 16);  // RNE
}
__device__ __forceinline__ float bf2f(u16 h) {
  return __uint_as_float(((unsigned int)h) << 16);
}

// XCD-chunked bijective swizzle (nwg % 8 == 0): consecutive work ids land on
// the same XCD so operand panels stay in that XCD's L2.
__device__ __forceinline__ int xcd_swz(int x, int nwg) {
  return (x & 7) * (nwg >> 3) + (x >> 3);
}

__device__ __forceinline__ void gload_lds16(const u16* g, u16* l) {
  __builtin_amdgcn_global_load_lds(
      (__attribute__((address_space(1))) void*)(g),
      (__attribute__((address_space(3))) void*)(l), 16, 0, 0);
}

__device__ __forceinline__ f32x4 mfma_bf16(short8 a, short8 b, f32x4 c) {
  asm("v_mfma_f32_16x16x32_bf16 %0, %1, %2, %0" : "+v"(c) : "v"(a), "v"(b));
  return c;
}

// ================= 256x256 8-wave GEMM core =================
// C(256x256) += A(256xK) * Bt(256xK)^T. 512 threads = 8 waves (2M x 4N),
// per-wave 128x64 = 8x4 16x16 frags. BK=64, double-buffered LDS (128KB).
// LDS layout per operand tile [256][64] bf16: 16x32-subtiled, byte-swizzled
// (bit5 ^= bit9 within each 1KB subtile), realized by pre-swizzled global src.
// Issue order per tile: B0,B1,B2,B3,A0,A1,A2,A3 (8KB each).
// Waits: tile entry vmcnt(1) [A3 may fly; consumed ph2/3]; mid-tile vmcnt(4).
__device__ __forceinline__ void gemm256_core(const u16* __restrict__ Ag,
                                             const u16* __restrict__ Bg,
                                             int NT, size_t lda, size_t ldb,
                                             u16* sm, f32x4 (&acc)[8][4]) {
  const int tid = threadIdx.x;
  const int lane = tid & 63;
  const int wid = tid >> 6;   // 0..7
  const int wm = wid >> 2;    // 0..1
  const int wn = wid & 3;     // 0..3
  const int wm8 = wm << 3;
  const int wn4 = wn << 2;

  u16* sA = sm;            // [2][16384] u16 (32KB per buf)
  u16* sB = sm + 32768;

  // staging decode: thread covers LDS bytes j*8192 + tid*16 of each operand tile.
  // b' = lane*16 ; b = b' ^ (bit9(b')<<5) ; r_in_sub = b>>6 ; c_in_sub = (b&63)>>1
  const int bb = (lane << 4) ^ (((lane >> 5) & 1) << 5);
  const int rins = bb >> 6;
  const int cins = (bb & 63) >> 1;
  const int s0 = wid, s1 = 8 + wid, s2 = 16 + wid, s3 = 24 + wid;
  const size_t aoff0 = (size_t)((s0 >> 1) * 16 + rins) * lda + ((s0 & 1) * 32 + cins);
  const size_t aoff1 = (size_t)((s1 >> 1) * 16 + rins) * lda + ((s1 & 1) * 32 + cins);
  const size_t aoff2 = (size_t)((s2 >> 1) * 16 + rins) * lda + ((s2 & 1) * 32 + cins);
  const size_t aoff3 = (size_t)((s3 >> 1) * 16 + rins) * lda + ((s3 & 1) * 32 + cins);
  const size_t boff0 = (size_t)((s0 >> 1) * 16 + rins) * ldb + ((s0 & 1) * 32 + cins);
  const size_t boff1 = (size_t)((s1 >> 1) * 16 + rins) * ldb + ((s1 & 1) * 32 + cins);
  const size_t boff2 = (size_t)((s2 >> 1) * 16 + rins) * ldb + ((s2 & 1) * 32 + cins);
  const size_t boff3 = (size_t)((s3 >> 1) * 16 + rins) * ldb + ((s3 & 1) * 32 + cins);
  const int wid512 = wid << 9;  // wid*512 u16 = wid*1024 bytes

  // fragment read offset (u16): lane_off = (l&15)*64 + (l>>4)*16 bytes, swizzled
  const int lof = ((lane & 15) << 6) + ((lane >> 4) << 4);
  const int loe = (lof ^ (((lane >> 3) & 1) << 5)) >> 1;

#define ISSUE_A(j, nb, kt) \
  gload_lds16(Ag + aoff##j + (size_t)(kt) * 64, sA + (nb) * 16384 + (j) * 4096 + wid512)
#define ISSUE_B(j, nb, kt) \
  gload_lds16(Bg + boff##j + (size_t)(kt) * 64, sB + (nb) * 16384 + (j) * 4096 + wid512)

  // prologue: stage tile 0 into buf 0
  ISSUE_B(0, 0, 0); ISSUE_B(1, 0, 0); ISSUE_B(2, 0, 0); ISSUE_B(3, 0, 0);
  ISSUE_A(0, 0, 0); ISSUE_A(1, 0, 0); ISSUE_A(2, 0, 0); ISSUE_A(3, 0, 0);

  int buf = 0;
  for (int kt = 0; kt < NT; ++kt) {
    const int nk = kt + 1;
    const bool pre = nk < NT;
    const int nb = buf ^ 1;
    asm volatile("s_waitcnt vmcnt(1)" ::: "memory");
    __builtin_amdgcn_s_barrier();
    asm volatile("" ::: "memory");
    const u16* bufA = sA + buf * 16384;
    const u16* bufB = sB + buf * 16384;
    short8 bf[4][2];
#pragma unroll
    for (int n = 0; n < 4; ++n) {
      bf[n][0] = *(const short8*)(bufB + (wn4 + n) * 1024 + loe);
      bf[n][1] = *(const short8*)(bufB + (wn4 + n) * 1024 + 512 + loe);
    }
    // ---- phase 0 (m0,m1)
    {
      short8 af[2][2];
#pragma unroll
      for (int m = 0; m < 2; ++m) {
        af[m][0] = *(const short8*)(bufA + (wm8 + m) * 1024 + loe);
        af[m][1] = *(const short8*)(bufA + (wm8 + m) * 1024 + 512 + loe);
      }
      if (pre) { ISSUE_B(0, nb, nk); ISSUE_B(1, nb, nk); }
      __builtin_amdgcn_s_setprio(1);
#pragma unroll
      for (int m = 0; m < 2; ++m)
#pragma unroll
        for (int n = 0; n < 4; ++n) {
          acc[m][n] = mfma_bf16(af[m][0], bf[n][0], acc[m][n]);
          acc[m][n] = mfma_bf16(af[m][1], bf[n][1], acc[m][n]);
        }
      __builtin_amdgcn_s_setprio(0);
    }
    // ---- phase 1 (m2,m3)
    {
      short8 af[2][2];
#pragma unroll
      for (int m = 0; m < 2; ++m) {
        af[m][0] = *(const short8*)(bufA + (wm8 + 2 + m) * 1024 + loe);
        af[m][1] = *(const short8*)(bufA + (wm8 + 2 + m) * 1024 + 512 + loe);
      }
      if (pre) { ISSUE_B(2, nb, nk); ISSUE_B(3, nb, nk); }
      __builtin_amdgcn_s_setprio(1);
#pragma unroll
      for (int m = 0; m < 2; ++m)
#pragma unroll
        for (int n = 0; n < 4; ++n) {
          acc[2 + m][n] = mfma_bf16(af[m][0], bf[n][0], acc[2 + m][n]);
          acc[2 + m][n] = mfma_bf16(af[m][1], bf[n][1], acc[2 + m][n]);
        }
      __builtin_amdgcn_s_setprio(0);
    }
    // ---- mid-tile: A of current tile must fully land (A-half-2 used next)
    if (pre) {
      asm volatile("s_waitcnt vmcnt(4)" ::: "memory");
    } else {
      asm volatile("s_waitcnt vmcnt(0)" ::: "memory");
    }
    __builtin_amdgcn_s_barrier();
    asm volatile("" ::: "memory");
    // ---- phase 2 (m4,m5)
    {
      short8 af[2][2];
#pragma unroll
      for (int m = 0; m < 2; ++m) {
        af[m][0] = *(const short8*)(bufA + (wm8 + 4 + m) * 1024 + loe);
        af[m][1] = *(const short8*)(bufA + (wm8 + 4 + m) * 1024 + 512 + loe);
      }
      if (pre) { ISSUE_A(0, nb, nk); ISSUE_A(1, nb, nk); }
      __builtin_amdgcn_s_setprio(1);
#pragma unroll
      for (int m = 0; m < 2; ++m)
#pragma unroll
        for (int n = 0; n < 4; ++n) {
          acc[4 + m][n] = mfma_bf16(af[m][0], bf[n][0], acc[4 + m][n]);
          acc[4 + m][n] = mfma_bf16(af[m][1], bf[n][1], acc[4 + m][n]);
        }
      __builtin_amdgcn_s_setprio(0);
    }
    // ---- phase 3 (m6,m7)
    {
      short8 af[2][2];
#pragma unroll
      for (int m = 0; m < 2; ++m) {
        af[m][0] = *(const short8*)(bufA + (wm8 + 6 + m) * 1024 + loe);
        af[m][1] = *(const short8*)(bufA + (wm8 + 6 + m) * 1024 + 512 + loe);
      }
      if (pre) { ISSUE_A(2, nb, nk); ISSUE_A(3, nb, nk); }
      __builtin_amdgcn_s_setprio(1);
#pragma unroll
      for (int m = 0; m < 2; ++m)
#pragma unroll
        for (int n = 0; n < 4; ++n) {
          acc[6 + m][n] = mfma_bf16(af[m][0], bf[n][0], acc[6 + m][n]);
          acc[6 + m][n] = mfma_bf16(af[m][1], bf[n][1], acc[6 + m][n]);
        }
      __builtin_amdgcn_s_setprio(0);
    }
    buf ^= 1;
  }
  asm volatile("s_nop 7\n\ts_nop 7\n\ts_nop 7" ::);  // MFMA->VALU hazard guard
#undef ISSUE_A
#undef ISSUE_B
}

// ---- emb fp32 -> A2 = [hi | lo] stacked rows [16384][2048]
__global__ __launch_bounds__(256) void cvt_emb2_kernel(const float* __restrict__ in,
                                                       u16* __restrict__ A2) {
  int i = blockIdx.x * 256 + threadIdx.x;  // over 4M float4
  float4 v = ((const float4*)in)[i];
  int r = i >> 8;
  int c = (i & 255) << 2;
  u16x4 h, l;
#pragma unroll
  for (int j = 0; j < 4; ++j) {
    float x = (j == 0) ? v.x : (j == 1) ? v.y : (j == 2) ? v.z : v.w;
    u16 hb = f2bf(x);
    h[j] = hb;
    l[j] = f2bf(x - bf2f(hb));
  }
  *(u16x4*)(A2 + (size_t)r * 2048 + c) = h;
  *(u16x4*)(A2 + (size_t)r * 2048 + 1024 + c) = l;
}

// ---- W fp32 -> B = [Wh | Wh] stacked rows [1024][2048]
__global__ __launch_bounds__(256) void cvt_wstack_kernel(const float* __restrict__ in,
                                                         u16* __restrict__ B) {
  int i = blockIdx.x * 256 + threadIdx.x;  // over 256K float4
  float4 v = ((const float4*)in)[i];
  int r = i >> 8;
  int c = (i & 255) << 2;
  u16x4 h;
  h[0] = f2bf(v.x); h[1] = f2bf(v.y); h[2] = f2bf(v.z); h[3] = f2bf(v.w);
  *(u16x4*)(B + (size_t)r * 2048 + c) = h;
  *(u16x4*)(B + (size_t)r * 2048 + 1024 + c) = h;
}

// ---- Wv fp32 -> bf16 [1024][1024]
__global__ __launch_bounds__(256) void cvt_w_kernel(const float* __restrict__ in,
                                                    u16* __restrict__ B) {
  int i = blockIdx.x * 256 + threadIdx.x;
  float4 v = ((const float4*)in)[i];
  int r = i >> 8;
  int c = (i & 255) << 2;
  u16x4 h;
  h[0] = f2bf(v.x); h[1] = f2bf(v.y); h[2] = f2bf(v.z); h[3] = f2bf(v.w);
  *(u16x4*)(B + (size_t)r * 1024 + c) = h;
}

// ---- fused projections (flat grid 768, XCD-swizzled):
// z=0: q = emb2 @ [Wq|Wq]^T (K=2048)   z=1: k likewise
// z=2: vT[b][d][k] = Wv @ emb_hi^T (K=1024) -- transpose for free via operand swap
__global__ __launch_bounds__(512) void proj256_kernel(const u16* __restrict__ A2,
                                                      const u16* __restrict__ Bq,
                                                      const u16* __restrict__ Bk,
                                                      const u16* __restrict__ Bv,
                                                      const float* __restrict__ bq,
                                                      const float* __restrict__ bk,
                                                      const float* __restrict__ bv,
                                                      u16* __restrict__ q16,
                                                      u16* __restrict__ k16,
                                                      u16* __restrict__ vT) {
  __shared__ __align__(16) u16 sm[65536];  // 128KB
  const int wg = xcd_swz(blockIdx.x, 768);
  const int z = wg >> 8;
  const int r = wg & 255;
  const u16 *Ag, *Bg;
  size_t lda, ldb;
  int NT, m0, n0;
  if (z < 2) {
    m0 = (r >> 2) * 256;            // over MROWS (A-band shared by 4 consecutive)
    n0 = (r & 3) * 256;             // over DIM (weights, L2-resident)
    Ag = A2 + (size_t)m0 * 2048; lda = 2048;
    Bg = (z ? Bk : Bq) + (size_t)n0 * 2048; ldb = 2048;
    NT = 32;
  } else {
    m0 = (r & 3) * 256;             // over DIM (Wv bands, L2-resident)
    n0 = (r >> 2) * 256;            // over MROWS (emb streamed once)
    Ag = Bv + (size_t)m0 * 1024; lda = 1024;
    Bg = A2 + (size_t)n0 * 2048; ldb = 2048;  // emb hi = first 1024 cols
    NT = 16;
  }
  f32x4 acc[8][4] = {};
  gemm256_core(Ag, Bg, NT, lda, ldb, sm, acc);
  const int lane = threadIdx.x & 63, wid = threadIdx.x >> 6;
  const int rb = m0 + ((wid >> 2) << 7) + ((lane >> 4) << 2);
  const int cb = n0 + ((wid & 3) << 6) + (lane & 15);
  if (z < 2) {
    const float* bias = z ? bk : bq;
    u16* dst = z ? k16 : q16;
#pragma unroll
    for (int m = 0; m < 8; ++m)
#pragma unroll
      for (int n = 0; n < 4; ++n)
#pragma unroll
        for (int j = 0; j < 4; ++j) {
          int row = rb + m * 16 + j;
          int col = cb + n * 16;
          dst[(size_t)row * DIM + col] = f2bf(acc[m][n][j] + bias[col]);
        }
  } else {
#pragma unroll
    for (int m = 0; m < 8; ++m)
#pragma unroll
      for (int n = 0; n < 4; ++n)
#pragma unroll
        for (int j = 0; j < 4; ++j) {
          int d = rb + m * 16 + j;     // 0..1023
          int kg = cb + n * 16;        // 0..16383
          int bi = kg >> 11, s = kg & 2047;
          vT[((size_t)bi << 21) + ((size_t)d << 11) + s] = f2bf(acc[m][n][j] + bv[d]);
        }
  }
}

// ---- scores: scF = (q.k^T + mask) / 32  (fp32) ; flat grid 512, one batch/XCD
__global__ __launch_bounds__(512) void scores256_kernel(const u16* __restrict__ q16,
                                                        const u16* __restrict__ k16,
                                                        const float* __restrict__ mask,
                                                        float* __restrict__ scF) {
  __shared__ __align__(16) u16 sm[65536];
  const int wg = xcd_swz(blockIdx.x, 512);
  const int b = wg >> 6;
  const int m0 = ((wg >> 3) & 7) * 256;
  const int n0 = (wg & 7) * 256;
  f32x4 acc[8][4] = {};
  gemm256_core(q16 + ((size_t)b * SEQ + m0) * DIM, k16 + ((size_t)b * SEQ + n0) * DIM,
               16, DIM, DIM, sm, acc);
  const int lane = threadIdx.x & 63, wid = threadIdx.x >> 6;
  const int rb = m0 + ((wid >> 2) << 7) + ((lane >> 4) << 2);
  const int cb = n0 + ((wid & 3) << 6) + (lane & 15);
#pragma unroll
  for (int m = 0; m < 8; ++m)
#pragma unroll
    for (int n = 0; n < 4; ++n)
#pragma unroll
      for (int j = 0; j < 4; ++j) {
        size_t idx = ((size_t)b * SEQ + rb + m * 16 + j) * SEQ + (cb + n * 16);
        scF[idx] = (acc[m][n][j] + mask[idx]) * 0.03125f;
      }
}

// ---- PV: out = probs @ v^T ; probs bf16 at row stride 4096 u16 inside scF
__global__ __launch_bounds__(512) void pv256_kernel(const u16* __restrict__ pr,
                                                    const u16* __restrict__ vt,
                                                    float* __restrict__ out) {
  __shared__ __align__(16) u16 sm[65536];
  const int wg = xcd_swz(blockIdx.x, 256);
  const int b = wg >> 5;
  const int m0 = ((wg >> 2) & 7) * 256;
  const int n0 = (wg & 3) * 256;
  f32x4 acc[8][4] = {};
  gemm256_core(pr + ((size_t)b * SEQ + m0) * (2 * SEQ), vt + ((size_t)b * DIM + n0) * SEQ,
               32, 2 * SEQ, SEQ, sm, acc);
  const int lane = threadIdx.x & 63, wid = threadIdx.x >> 6;
  const int rb = m0 + ((wid >> 2) << 7) + ((lane >> 4) << 2);
  const int cb = n0 + ((wid & 3) << 6) + (lane & 15);
#pragma unroll
  for (int m = 0; m < 8; ++m)
#pragma unroll
    for (int n = 0; n < 4; ++n)
#pragma unroll
      for (int j = 0; j < 4; ++j)
        out[((size_t)b * SEQ + rb + m * 16 + j) * DIM + (cb + n * 16)] = acc[m][n][j];
}

// ---- fp32 row softmax; writes bf16 probs in place into row-local first half
__global__ __launch_bounds__(256) void softmax_kernel(float* __restrict__ scF) {
  __shared__ float red[8];
  const size_t row = blockIdx.x;
  float* rowp = scF + row * SEQ;
  const int tid = threadIdx.x;
  float4 v0 = ((const float4*)rowp)[2 * tid];
  float4 v1 = ((const float4*)rowp)[2 * tid + 1];
  float f[8] = {v0.x, v0.y, v0.z, v0.w, v1.x, v1.y, v1.z, v1.w};
  float mx = f[0];
#pragma unroll
  for (int j = 1; j < 8; ++j) mx = fmaxf(mx, f[j]);
#pragma unroll
  for (int off = 1; off < 64; off <<= 1) mx = fmaxf(mx, __shfl_xor(mx, off));
  const int wid = tid >> 6, lane = tid & 63;
  if (lane == 0) red[wid] = mx;
  __syncthreads();
  mx = fmaxf(fmaxf(red[0], red[1]), fmaxf(red[2], red[3]));
  float e[8];
  float s = 0.f;
#pragma unroll
  for (int j = 0; j < 8; ++j) {
    e[j] = __expf(f[j] - mx);
    s += e[j];
  }
#pragma unroll
  for (int off = 1; off < 64; off <<= 1) s += __shfl_xor(s, off);
  if (lane == 0) red[4 + wid] = s;
  __syncthreads();
  s = (red[4] + red[5]) + (red[6] + red[7]);
  const float inv = 1.f / s;
  short8 o;
#pragma unroll
  for (int j = 0; j < 8; ++j) o[j] = (short)f2bf(e[j] * inv);
  *(short8*)((u16*)rowp + tid * 8) = o;
}

extern "C" void kernel_launch(void* const* d_in, const int* in_sizes, int n_in,
                              void* d_out, int out_size, void* d_ws, size_t ws_size,
                              hipStream_t stream) {
  const float* emb  = (const float*)d_in[0];
  const float* mask = (const float*)d_in[1];
  const float* Wq   = (const float*)d_in[2];
  const float* bq   = (const float*)d_in[3];
  const float* Wk   = (const float*)d_in[4];
  const float* bk   = (const float*)d_in[5];
  const float* Wv   = (const float*)d_in[6];
  const float* bv   = (const float*)d_in[7];
  float* out = (float*)d_out;

  const size_t M1 = 1024 * 1024;
  float* scF = (float*)d_ws;                 // 32M fp32 (128MB)
  u16* A2  = (u16*)d_ws + 64 * M1;           // 32M u16: [emb_hi | emb_lo]
  u16* Bq  = A2 + 32 * M1;                   // 2M
  u16* Bk  = Bq + 2 * M1;                    // 2M
  u16* Bv  = Bk + 2 * M1;                    // 1M
  u16* q16 = Bv + 1 * M1;                    // 16M
  u16* k16 = q16 + 16 * M1;                  // 16M
  u16* vT  = k16 + 16 * M1;                  // 16M  (ends at 149M u16 = 298MB)

  cvt_emb2_kernel<<<16384, 256, 0, stream>>>(emb, A2);
  cvt_wstack_kernel<<<1024, 256, 0, stream>>>(Wq, Bq);
  cvt_wstack_kernel<<<1024, 256, 0, stream>>>(Wk, Bk);
  cvt_w_kernel<<<1024, 256, 0, stream>>>(Wv, Bv);

  proj256_kernel<<<768, 512, 0, stream>>>(A2, Bq, Bk, Bv, bq, bk, bv, q16, k16, vT);

  scores256_kernel<<<512, 512, 0, stream>>>(q16, k16, mask, scF);
  softmax_kernel<<<MROWS, 256, 0, stream>>>(scF);
  pv256_kernel<<<256, 512, 0, stream>>>((const u16*)scF, vT, out);
}

// Round 5
// 380.131 us; speedup vs baseline: 1.3616x; 1.0460x over previous
//
#include <hip/hip_runtime.h>

// SelfAttention: B=8, S=2048, D=1024, fp32 in/out.
// GEMMs on a 256x256-tile, 8-wave, BK=64 double-buffered MFMA core with
// swizzled LDS (pre-swizzled global staging), counted vmcnt, setprio,
// XCD-chunked block swizzle (T1). Projections split into two uniform-work
// kernels (qk: NT=32 x512 blocks; v: NT=16 x256 blocks) for XCD balance.
// V is projected directly transposed (vT = Wv @ emb^T).
// Q/K precision: stacked-K [emb_hi | emb_lo] @ [Wh | Wh] = (eh+el)*Wh.
// Scores/softmax in fp32; probs bf16 in-place; PV bf16 MFMA.
// d_ws (u16 units): scF fp32[32M]=64M | A2[32M] | Bq[2M] Bk[2M] Bv[1M] |
//   q16[16M] k16[16M] vT[16M]. Total 149M u16 = 298MB.

#define B_SZ 8
#define SEQ  2048
#define DIM  1024
#define MROWS (B_SZ * SEQ)  // 16384

typedef unsigned short u16;
typedef short short8 __attribute__((ext_vector_type(8)));
typedef unsigned short u16x4 __attribute__((ext_vector_type(4)));
typedef float f32x4 __attribute__((ext_vector_type(4)));

__device__ __forceinline__ u16 f2bf(float x) {
  unsigned int u = __float_as_uint(x);
  return (u16)((u + 0x7fffu + ((u >> 16) & 1u)) >> 16);  // RNE
}
__device__ __forceinline__ float bf2f(u16 h) {
  return __uint_as_float(((unsigned int)h) << 16);
}

// XCD-chunked bijective swizzle (nwg % 8 == 0): consecutive work ids land on
// the same XCD so operand panels stay in that XCD's L2.
__device__ __forceinline__ int xcd_swz(int x, int nwg) {
  return (x & 7) * (nwg >> 3) + (x >> 3);
}

__device__ __forceinline__ void gload_lds16(const u16* g, u16* l) {
  __builtin_amdgcn_global_load_lds(
      (__attribute__((address_space(1))) void*)(g),
      (__attribute__((address_space(3))) void*)(l), 16, 0, 0);
}

__device__ __forceinline__ f32x4 mfma_bf16(short8 a, short8 b, f32x4 c) {
  asm("v_mfma_f32_16x16x32_bf16 %0, %1, %2, %0" : "+v"(c) : "v"(a), "v"(b));
  return c;
}

// ================= 256x256 8-wave GEMM core =================
// C(256x256) += A(256xK) * Bt(256xK)^T. 512 threads = 8 waves (2M x 4N),
// per-wave 128x64 = 8x4 16x16 frags. BK=64, double-buffered LDS (128KB).
// LDS layout per operand tile [256][64] bf16: 16x32-subtiled, byte-swizzled
// (bit5 ^= bit9 within each 1KB subtile), realized by pre-swizzled global src.
// Issue order per tile: B0,B1,B2,B3,A0,A1,A2,A3 (8KB each).
// Waits: tile entry vmcnt(1) [A3 may fly; consumed ph2/3]; mid-tile vmcnt(4).
__device__ __forceinline__ void gemm256_core(const u16* __restrict__ Ag,
                                             const u16* __restrict__ Bg,
                                             int NT, size_t lda, size_t ldb,
                                             u16* sm, f32x4 (&acc)[8][4]) {
  const int tid = threadIdx.x;
  const int lane = tid & 63;
  const int wid = tid >> 6;   // 0..7
  const int wm = wid >> 2;    // 0..1
  const int wn = wid & 3;     // 0..3
  const int wm8 = wm << 3;
  const int wn4 = wn << 2;

  u16* sA = sm;            // [2][16384] u16 (32KB per buf)
  u16* sB = sm + 32768;

  // staging decode: thread covers LDS bytes j*8192 + tid*16 of each operand tile.
  // b' = lane*16 ; b = b' ^ (bit9(b')<<5) ; r_in_sub = b>>6 ; c_in_sub = (b&63)>>1
  const int bb = (lane << 4) ^ (((lane >> 5) & 1) << 5);
  const int rins = bb >> 6;
  const int cins = (bb & 63) >> 1;
  const int s0 = wid, s1 = 8 + wid, s2 = 16 + wid, s3 = 24 + wid;
  const size_t aoff0 = (size_t)((s0 >> 1) * 16 + rins) * lda + ((s0 & 1) * 32 + cins);
  const size_t aoff1 = (size_t)((s1 >> 1) * 16 + rins) * lda + ((s1 & 1) * 32 + cins);
  const size_t aoff2 = (size_t)((s2 >> 1) * 16 + rins) * lda + ((s2 & 1) * 32 + cins);
  const size_t aoff3 = (size_t)((s3 >> 1) * 16 + rins) * lda + ((s3 & 1) * 32 + cins);
  const size_t boff0 = (size_t)((s0 >> 1) * 16 + rins) * ldb + ((s0 & 1) * 32 + cins);
  const size_t boff1 = (size_t)((s1 >> 1) * 16 + rins) * ldb + ((s1 & 1) * 32 + cins);
  const size_t boff2 = (size_t)((s2 >> 1) * 16 + rins) * ldb + ((s2 & 1) * 32 + cins);
  const size_t boff3 = (size_t)((s3 >> 1) * 16 + rins) * ldb + ((s3 & 1) * 32 + cins);
  const int wid512 = wid << 9;  // wid*512 u16 = wid*1024 bytes

  // fragment read offset (u16): lane_off = (l&15)*64 + (l>>4)*16 bytes, swizzled
  const int lof = ((lane & 15) << 6) + ((lane >> 4) << 4);
  const int loe = (lof ^ (((lane >> 3) & 1) << 5)) >> 1;

#define ISSUE_A(j, nb, kt) \
  gload_lds16(Ag + aoff##j + (size_t)(kt) * 64, sA + (nb) * 16384 + (j) * 4096 + wid512)
#define ISSUE_B(j, nb, kt) \
  gload_lds16(Bg + boff##j + (size_t)(kt) * 64, sB + (nb) * 16384 + (j) * 4096 + wid512)

  // prologue: stage tile 0 into buf 0
  ISSUE_B(0, 0, 0); ISSUE_B(1, 0, 0); ISSUE_B(2, 0, 0); ISSUE_B(3, 0, 0);
  ISSUE_A(0, 0, 0); ISSUE_A(1, 0, 0); ISSUE_A(2, 0, 0); ISSUE_A(3, 0, 0);

  int buf = 0;
  for (int kt = 0; kt < NT; ++kt) {
    const int nk = kt + 1;
    const bool pre = nk < NT;
    const int nb = buf ^ 1;
    asm volatile("s_waitcnt vmcnt(1)" ::: "memory");
    __builtin_amdgcn_s_barrier();
    asm volatile("" ::: "memory");
    const u16* bufA = sA + buf * 16384;
    const u16* bufB = sB + buf * 16384;
    short8 bf[4][2];
#pragma unroll
    for (int n = 0; n < 4; ++n) {
      bf[n][0] = *(const short8*)(bufB + (wn4 + n) * 1024 + loe);
      bf[n][1] = *(const short8*)(bufB + (wn4 + n) * 1024 + 512 + loe);
    }
    // ---- phase 0 (m0,m1)
    {
      short8 af[2][2];
#pragma unroll
      for (int m = 0; m < 2; ++m) {
        af[m][0] = *(const short8*)(bufA + (wm8 + m) * 1024 + loe);
        af[m][1] = *(const short8*)(bufA + (wm8 + m) * 1024 + 512 + loe);
      }
      if (pre) { ISSUE_B(0, nb, nk); ISSUE_B(1, nb, nk); }
      __builtin_amdgcn_s_setprio(1);
#pragma unroll
      for (int m = 0; m < 2; ++m)
#pragma unroll
        for (int n = 0; n < 4; ++n) {
          acc[m][n] = mfma_bf16(af[m][0], bf[n][0], acc[m][n]);
          acc[m][n] = mfma_bf16(af[m][1], bf[n][1], acc[m][n]);
        }
      __builtin_amdgcn_s_setprio(0);
    }
    // ---- phase 1 (m2,m3)
    {
      short8 af[2][2];
#pragma unroll
      for (int m = 0; m < 2; ++m) {
        af[m][0] = *(const short8*)(bufA + (wm8 + 2 + m) * 1024 + loe);
        af[m][1] = *(const short8*)(bufA + (wm8 + 2 + m) * 1024 + 512 + loe);
      }
      if (pre) { ISSUE_B(2, nb, nk); ISSUE_B(3, nb, nk); }
      __builtin_amdgcn_s_setprio(1);
#pragma unroll
      for (int m = 0; m < 2; ++m)
#pragma unroll
        for (int n = 0; n < 4; ++n) {
          acc[2 + m][n] = mfma_bf16(af[m][0], bf[n][0], acc[2 + m][n]);
          acc[2 + m][n] = mfma_bf16(af[m][1], bf[n][1], acc[2 + m][n]);
        }
      __builtin_amdgcn_s_setprio(0);
    }
    // ---- mid-tile: A of current tile must fully land (A-half-2 used next)
    if (pre) {
      asm volatile("s_waitcnt vmcnt(4)" ::: "memory");
    } else {
      asm volatile("s_waitcnt vmcnt(0)" ::: "memory");
    }
    __builtin_amdgcn_s_barrier();
    asm volatile("" ::: "memory");
    // ---- phase 2 (m4,m5)
    {
      short8 af[2][2];
#pragma unroll
      for (int m = 0; m < 2; ++m) {
        af[m][0] = *(const short8*)(bufA + (wm8 + 4 + m) * 1024 + loe);
        af[m][1] = *(const short8*)(bufA + (wm8 + 4 + m) * 1024 + 512 + loe);
      }
      if (pre) { ISSUE_A(0, nb, nk); ISSUE_A(1, nb, nk); }
      __builtin_amdgcn_s_setprio(1);
#pragma unroll
      for (int m = 0; m < 2; ++m)
#pragma unroll
        for (int n = 0; n < 4; ++n) {
          acc[4 + m][n] = mfma_bf16(af[m][0], bf[n][0], acc[4 + m][n]);
          acc[4 + m][n] = mfma_bf16(af[m][1], bf[n][1], acc[4 + m][n]);
        }
      __builtin_amdgcn_s_setprio(0);
    }
    // ---- phase 3 (m6,m7)
    {
      short8 af[2][2];
#pragma unroll
      for (int m = 0; m < 2; ++m) {
        af[m][0] = *(const short8*)(bufA + (wm8 + 6 + m) * 1024 + loe);
        af[m][1] = *(const short8*)(bufA + (wm8 + 6 + m) * 1024 + 512 + loe);
      }
      if (pre) { ISSUE_A(2, nb, nk); ISSUE_A(3, nb, nk); }
      __builtin_amdgcn_s_setprio(1);
#pragma unroll
      for (int m = 0; m < 2; ++m)
#pragma unroll
        for (int n = 0; n < 4; ++n) {
          acc[6 + m][n] = mfma_bf16(af[m][0], bf[n][0], acc[6 + m][n]);
          acc[6 + m][n] = mfma_bf16(af[m][1], bf[n][1], acc[6 + m][n]);
        }
      __builtin_amdgcn_s_setprio(0);
    }
    buf ^= 1;
  }
  asm volatile("s_nop 7\n\ts_nop 7\n\ts_nop 7" ::);  // MFMA->VALU hazard guard
#undef ISSUE_A
#undef ISSUE_B
}

// ---- emb fp32 -> A2 = [hi | lo] stacked rows [16384][2048]
__global__ __launch_bounds__(256) void cvt_emb2_kernel(const float* __restrict__ in,
                                                       u16* __restrict__ A2) {
  int i = blockIdx.x * 256 + threadIdx.x;  // over 4M float4
  float4 v = ((const float4*)in)[i];
  int r = i >> 8;
  int c = (i & 255) << 2;
  u16x4 h, l;
#pragma unroll
  for (int j = 0; j < 4; ++j) {
    float x = (j == 0) ? v.x : (j == 1) ? v.y : (j == 2) ? v.z : v.w;
    u16 hb = f2bf(x);
    h[j] = hb;
    l[j] = f2bf(x - bf2f(hb));
  }
  *(u16x4*)(A2 + (size_t)r * 2048 + c) = h;
  *(u16x4*)(A2 + (size_t)r * 2048 + 1024 + c) = l;
}

// ---- W fp32 -> B = [Wh | Wh] stacked rows [1024][2048]
__global__ __launch_bounds__(256) void cvt_wstack_kernel(const float* __restrict__ in,
                                                         u16* __restrict__ B) {
  int i = blockIdx.x * 256 + threadIdx.x;  // over 256K float4
  float4 v = ((const float4*)in)[i];
  int r = i >> 8;
  int c = (i & 255) << 2;
  u16x4 h;
  h[0] = f2bf(v.x); h[1] = f2bf(v.y); h[2] = f2bf(v.z); h[3] = f2bf(v.w);
  *(u16x4*)(B + (size_t)r * 2048 + c) = h;
  *(u16x4*)(B + (size_t)r * 2048 + 1024 + c) = h;
}

// ---- Wv fp32 -> bf16 [1024][1024]
__global__ __launch_bounds__(256) void cvt_w_kernel(const float* __restrict__ in,
                                                    u16* __restrict__ B) {
  int i = blockIdx.x * 256 + threadIdx.x;
  float4 v = ((const float4*)in)[i];
  int r = i >> 8;
  int c = (i & 255) << 2;
  u16x4 h;
  h[0] = f2bf(v.x); h[1] = f2bf(v.y); h[2] = f2bf(v.z); h[3] = f2bf(v.w);
  *(u16x4*)(B + (size_t)r * 1024 + c) = h;
}

// ---- Q/K projection (flat grid 512, XCD-swizzled, uniform NT=32):
// wg decode: band = wg>>3 -> m0 ; inner = wg&7: z = inner>>2, n0 = (inner&3)*256.
// Each XCD chunk = 8 contiguous A-bands x (2z x 4n): A-band reused 8x in-L2.
__global__ __launch_bounds__(512) void proj_qk256_kernel(const u16* __restrict__ A2,
                                                         const u16* __restrict__ Bq,
                                                         const u16* __restrict__ Bk,
                                                         const float* __restrict__ bq,
                                                         const float* __restrict__ bk,
                                                         u16* __restrict__ q16,
                                                         u16* __restrict__ k16) {
  __shared__ __align__(16) u16 sm[65536];  // 128KB
  const int wg = xcd_swz(blockIdx.x, 512);
  const int m0 = (wg >> 3) * 256;
  const int inner = wg & 7;
  const int z = inner >> 2;
  const int n0 = (inner & 3) * 256;
  const u16* Ag = A2 + (size_t)m0 * 2048;
  const u16* Bg = (z ? Bk : Bq) + (size_t)n0 * 2048;
  f32x4 acc[8][4] = {};
  gemm256_core(Ag, Bg, 32, 2048, 2048, sm, acc);
  const int lane = threadIdx.x & 63, wid = threadIdx.x >> 6;
  const int rb = m0 + ((wid >> 2) << 7) + ((lane >> 4) << 2);
  const int cb = n0 + ((wid & 3) << 6) + (lane & 15);
  const float* bias = z ? bk : bq;
  u16* dst = z ? k16 : q16;
#pragma unroll
  for (int m = 0; m < 8; ++m)
#pragma unroll
    for (int n = 0; n < 4; ++n)
#pragma unroll
      for (int j = 0; j < 4; ++j) {
        int row = rb + m * 16 + j;
        int col = cb + n * 16;
        dst[(size_t)row * DIM + col] = f2bf(acc[m][n][j] + bias[col]);
      }
}

// ---- V projection, transposed output (flat grid 256, uniform NT=16):
// vT[b][d][k] = Wv @ emb_hi^T. wg decode: m0 = (wg&3)*256 (d), n0 = (wg>>2)*256 (rows).
__global__ __launch_bounds__(512) void proj_v256_kernel(const u16* __restrict__ A2,
                                                        const u16* __restrict__ Bv,
                                                        const float* __restrict__ bv,
                                                        u16* __restrict__ vT) {
  __shared__ __align__(16) u16 sm[65536];
  const int wg = xcd_swz(blockIdx.x, 256);
  const int m0 = (wg & 3) * 256;   // over DIM (Wv bands, reused in-L2)
  const int n0 = (wg >> 2) * 256;  // over MROWS (emb streamed once)
  const u16* Ag = Bv + (size_t)m0 * 1024;
  const u16* Bg = A2 + (size_t)n0 * 2048;  // emb hi = first 1024 cols
  f32x4 acc[8][4] = {};
  gemm256_core(Ag, Bg, 16, 1024, 2048, sm, acc);
  const int lane = threadIdx.x & 63, wid = threadIdx.x >> 6;
  const int rb = m0 + ((wid >> 2) << 7) + ((lane >> 4) << 2);
  const int cb = n0 + ((wid & 3) << 6) + (lane & 15);
#pragma unroll
  for (int m = 0; m < 8; ++m)
#pragma unroll
    for (int n = 0; n < 4; ++n)
#pragma unroll
      for (int j = 0; j < 4; ++j) {
        int d = rb + m * 16 + j;     // 0..1023
        int kg = cb + n * 16;        // 0..16383
        int bi = kg >> 11, s = kg & 2047;
        vT[((size_t)bi << 21) + ((size_t)d << 11) + s] = f2bf(acc[m][n][j] + bv[d]);
      }
}

// ---- scores: scF = (q.k^T + mask) / 32  (fp32) ; flat grid 512, one batch/XCD
__global__ __launch_bounds__(512) void scores256_kernel(const u16* __restrict__ q16,
                                                        const u16* __restrict__ k16,
                                                        const float* __restrict__ mask,
                                                        float* __restrict__ scF) {
  __shared__ __align__(16) u16 sm[65536];
  const int wg = xcd_swz(blockIdx.x, 512);
  const int b = wg >> 6;
  const int m0 = ((wg >> 3) & 7) * 256;
  const int n0 = (wg & 7) * 256;
  f32x4 acc[8][4] = {};
  gemm256_core(q16 + ((size_t)b * SEQ + m0) * DIM, k16 + ((size_t)b * SEQ + n0) * DIM,
               16, DIM, DIM, sm, acc);
  const int lane = threadIdx.x & 63, wid = threadIdx.x >> 6;
  const int rb = m0 + ((wid >> 2) << 7) + ((lane >> 4) << 2);
  const int cb = n0 + ((wid & 3) << 6) + (lane & 15);
#pragma unroll
  for (int m = 0; m < 8; ++m)
#pragma unroll
    for (int n = 0; n < 4; ++n)
#pragma unroll
      for (int j = 0; j < 4; ++j) {
        size_t idx = ((size_t)b * SEQ + rb + m * 16 + j) * SEQ + (cb + n * 16);
        scF[idx] = (acc[m][n][j] + mask[idx]) * 0.03125f;
      }
}

// ---- PV: out = probs @ v^T ; probs bf16 at row stride 4096 u16 inside scF
__global__ __launch_bounds__(512) void pv256_kernel(const u16* __restrict__ pr,
                                                    const u16* __restrict__ vt,
                                                    float* __restrict__ out) {
  __shared__ __align__(16) u16 sm[65536];
  const int wg = xcd_swz(blockIdx.x, 256);
  const int b = wg >> 5;
  const int m0 = ((wg >> 2) & 7) * 256;
  const int n0 = (wg & 3) * 256;
  f32x4 acc[8][4] = {};
  gemm256_core(pr + ((size_t)b * SEQ + m0) * (2 * SEQ), vt + ((size_t)b * DIM + n0) * SEQ,
               32, 2 * SEQ, SEQ, sm, acc);
  const int lane = threadIdx.x & 63, wid = threadIdx.x >> 6;
  const int rb = m0 + ((wid >> 2) << 7) + ((lane >> 4) << 2);
  const int cb = n0 + ((wid & 3) << 6) + (lane & 15);
#pragma unroll
  for (int m = 0; m < 8; ++m)
#pragma unroll
    for (int n = 0; n < 4; ++n)
#pragma unroll
      for (int j = 0; j < 4; ++j)
        out[((size_t)b * SEQ + rb + m * 16 + j) * DIM + (cb + n * 16)] = acc[m][n][j];
}

// ---- fp32 row softmax; writes bf16 probs in place into row-local first half
__global__ __launch_bounds__(256) void softmax_kernel(float* __restrict__ scF) {
  __shared__ float red[8];
  const size_t row = blockIdx.x;
  float* rowp = scF + row * SEQ;
  const int tid = threadIdx.x;
  float4 v0 = ((const float4*)rowp)[2 * tid];
  float4 v1 = ((const float4*)rowp)[2 * tid + 1];
  float f[8] = {v0.x, v0.y, v0.z, v0.w, v1.x, v1.y, v1.z, v1.w};
  float mx = f[0];
#pragma unroll
  for (int j = 1; j < 8; ++j) mx = fmaxf(mx, f[j]);
#pragma unroll
  for (int off = 1; off < 64; off <<= 1) mx = fmaxf(mx, __shfl_xor(mx, off));
  const int wid = tid >> 6, lane = tid & 63;
  if (lane == 0) red[wid] = mx;
  __syncthreads();
  mx = fmaxf(fmaxf(red[0], red[1]), fmaxf(red[2], red[3]));
  float e[8];
  float s = 0.f;
#pragma unroll
  for (int j = 0; j < 8; ++j) {
    e[j] = __expf(f[j] - mx);
    s += e[j];
  }
#pragma unroll
  for (int off = 1; off < 64; off <<= 1) s += __shfl_xor(s, off);
  if (lane == 0) red[4 + wid] = s;
  __syncthreads();
  s = (red[4] + red[5]) + (red[6] + red[7]);
  const float inv = 1.f / s;
  short8 o;
#pragma unroll
  for (int j = 0; j < 8; ++j) o[j] = (short)f2bf(e[j] * inv);
  *(short8*)((u16*)rowp + tid * 8) = o;
}

extern "C" void kernel_launch(void* const* d_in, const int* in_sizes, int n_in,
                              void* d_out, int out_size, void* d_ws, size_t ws_size,
                              hipStream_t stream) {
  const float* emb  = (const float*)d_in[0];
  const float* mask = (const float*)d_in[1];
  const float* Wq   = (const float*)d_in[2];
  const float* bq   = (const float*)d_in[3];
  const float* Wk   = (const float*)d_in[4];
  const float* bk   = (const float*)d_in[5];
  const float* Wv   = (const float*)d_in[6];
  const float* bv   = (const float*)d_in[7];
  float* out = (float*)d_out;

  const size_t M1 = 1024 * 1024;
  float* scF = (float*)d_ws;                 // 32M fp32 (128MB)
  u16* A2  = (u16*)d_ws + 64 * M1;           // 32M u16: [emb_hi | emb_lo]
  u16* Bq  = A2 + 32 * M1;                   // 2M
  u16* Bk  = Bq + 2 * M1;                    // 2M
  u16* Bv  = Bk + 2 * M1;                    // 1M
  u16* q16 = Bv + 1 * M1;                    // 16M
  u16* k16 = q16 + 16 * M1;                  // 16M
  u16* vT  = k16 + 16 * M1;                  // 16M  (ends at 149M u16 = 298MB)

  cvt_emb2_kernel<<<16384, 256, 0, stream>>>(emb, A2);
  cvt_wstack_kernel<<<1024, 256, 0, stream>>>(Wq, Bq);
  cvt_wstack_kernel<<<1024, 256, 0, stream>>>(Wk, Bk);
  cvt_w_kernel<<<1024, 256, 0, stream>>>(Wv, Bv);

  proj_qk256_kernel<<<512, 512, 0, stream>>>(A2, Bq, Bk, bq, bk, q16, k16);
  proj_v256_kernel<<<256, 512, 0, stream>>>(A2, Bv, bv, vT);

  scores256_kernel<<<512, 512, 0, stream>>>(q16, k16, mask, scF);
  softmax_kernel<<<MROWS, 256, 0, stream>>>(scF);
  pv256_kernel<<<256, 512, 0, stream>>>((const u16*)scF, vT, out);
}

// Round 6
// 326.036 us; speedup vs baseline: 1.5875x; 1.1659x over previous
//
#include <hip/hip_runtime.h>

// SelfAttention: B=8, S=2048, D=1024, fp32 in/out.
// GEMMs on a 256x256-tile, 8-wave, BK=64 double-buffered MFMA core with
// swizzled LDS (pre-swizzled global staging), counted vmcnt, setprio,
// XCD-chunked block swizzle (T1). Single merged projection kernel
// (uniform NT=16): q,k = emb@W^T; vT = Wv@emb^T (transpose for free).
// Precision: emb/W plain bf16 (r1->r2 showed residual terms don't move absmax;
// output floor is bf16-prob quantization). Scores/softmax in fp32; probs bf16
// in-place; PV bf16 MFMA.
// d_ws (u16 units): scF fp32[32M]=64M | emb16[16M] | Bq[1M] Bk[1M] Bv[1M] |
//   q16[16M] k16[16M] vT[16M]. Total 131M u16 = 262MB.

#define B_SZ 8
#define SEQ  2048
#define DIM  1024
#define MROWS (B_SZ * SEQ)  // 16384

typedef unsigned short u16;
typedef short short8 __attribute__((ext_vector_type(8)));
typedef unsigned short u16x4 __attribute__((ext_vector_type(4)));
typedef float f32x4 __attribute__((ext_vector_type(4)));

__device__ __forceinline__ u16 f2bf(float x) {
  unsigned int u = __float_as_uint(x);
  return (u16)((u + 0x7fffu + ((u >> 16) & 1u)) >> 16);  // RNE
}
__device__ __forceinline__ float bf2f(u16 h) {
  return __uint_as_float(((unsigned int)h) << 16);
}

// XCD-chunked bijective swizzle (nwg % 8 == 0): consecutive work ids land on
// the same XCD so operand panels stay in that XCD's L2.
__device__ __forceinline__ int xcd_swz(int x, int nwg) {
  return (x & 7) * (nwg >> 3) + (x >> 3);
}

__device__ __forceinline__ void gload_lds16(const u16* g, u16* l) {
  __builtin_amdgcn_global_load_lds(
      (__attribute__((address_space(1))) void*)(g),
      (__attribute__((address_space(3))) void*)(l), 16, 0, 0);
}

__device__ __forceinline__ f32x4 mfma_bf16(short8 a, short8 b, f32x4 c) {
  asm("v_mfma_f32_16x16x32_bf16 %0, %1, %2, %0" : "+v"(c) : "v"(a), "v"(b));
  return c;
}

// ================= 256x256 8-wave GEMM core =================
// C(256x256) += A(256xK) * Bt(256xK)^T. 512 threads = 8 waves (2M x 4N),
// per-wave 128x64 = 8x4 16x16 frags. BK=64, double-buffered LDS (128KB).
// LDS layout per operand tile [256][64] bf16: 16x32-subtiled, byte-swizzled
// (bit5 ^= bit9 within each 1KB subtile), realized by pre-swizzled global src.
// Issue order per tile: B0,B1,B2,B3,A0,A1,A2,A3 (8KB each).
// Waits: tile entry vmcnt(1) [A3 may fly; consumed ph2/3]; mid-tile vmcnt(4).
__device__ __forceinline__ void gemm256_core(const u16* __restrict__ Ag,
                                             const u16* __restrict__ Bg,
                                             int NT, size_t lda, size_t ldb,
                                             u16* sm, f32x4 (&acc)[8][4]) {
  const int tid = threadIdx.x;
  const int lane = tid & 63;
  const int wid = tid >> 6;   // 0..7
  const int wm = wid >> 2;    // 0..1
  const int wn = wid & 3;     // 0..3
  const int wm8 = wm << 3;
  const int wn4 = wn << 2;

  u16* sA = sm;            // [2][16384] u16 (32KB per buf)
  u16* sB = sm + 32768;

  // staging decode: thread covers LDS bytes j*8192 + tid*16 of each operand tile.
  // b' = lane*16 ; b = b' ^ (bit9(b')<<5) ; r_in_sub = b>>6 ; c_in_sub = (b&63)>>1
  const int bb = (lane << 4) ^ (((lane >> 5) & 1) << 5);
  const int rins = bb >> 6;
  const int cins = (bb & 63) >> 1;
  const int s0 = wid, s1 = 8 + wid, s2 = 16 + wid, s3 = 24 + wid;
  const size_t aoff0 = (size_t)((s0 >> 1) * 16 + rins) * lda + ((s0 & 1) * 32 + cins);
  const size_t aoff1 = (size_t)((s1 >> 1) * 16 + rins) * lda + ((s1 & 1) * 32 + cins);
  const size_t aoff2 = (size_t)((s2 >> 1) * 16 + rins) * lda + ((s2 & 1) * 32 + cins);
  const size_t aoff3 = (size_t)((s3 >> 1) * 16 + rins) * lda + ((s3 & 1) * 32 + cins);
  const size_t boff0 = (size_t)((s0 >> 1) * 16 + rins) * ldb + ((s0 & 1) * 32 + cins);
  const size_t boff1 = (size_t)((s1 >> 1) * 16 + rins) * ldb + ((s1 & 1) * 32 + cins);
  const size_t boff2 = (size_t)((s2 >> 1) * 16 + rins) * ldb + ((s2 & 1) * 32 + cins);
  const size_t boff3 = (size_t)((s3 >> 1) * 16 + rins) * ldb + ((s3 & 1) * 32 + cins);
  const int wid512 = wid << 9;  // wid*512 u16 = wid*1024 bytes

  // fragment read offset (u16): lane_off = (l&15)*64 + (l>>4)*16 bytes, swizzled
  const int lof = ((lane & 15) << 6) + ((lane >> 4) << 4);
  const int loe = (lof ^ (((lane >> 3) & 1) << 5)) >> 1;

#define ISSUE_A(j, nb, kt) \
  gload_lds16(Ag + aoff##j + (size_t)(kt) * 64, sA + (nb) * 16384 + (j) * 4096 + wid512)
#define ISSUE_B(j, nb, kt) \
  gload_lds16(Bg + boff##j + (size_t)(kt) * 64, sB + (nb) * 16384 + (j) * 4096 + wid512)

  // prologue: stage tile 0 into buf 0
  ISSUE_B(0, 0, 0); ISSUE_B(1, 0, 0); ISSUE_B(2, 0, 0); ISSUE_B(3, 0, 0);
  ISSUE_A(0, 0, 0); ISSUE_A(1, 0, 0); ISSUE_A(2, 0, 0); ISSUE_A(3, 0, 0);

  int buf = 0;
  for (int kt = 0; kt < NT; ++kt) {
    const int nk = kt + 1;
    const bool pre = nk < NT;
    const int nb = buf ^ 1;
    asm volatile("s_waitcnt vmcnt(1)" ::: "memory");
    __builtin_amdgcn_s_barrier();
    asm volatile("" ::: "memory");
    const u16* bufA = sA + buf * 16384;
    const u16* bufB = sB + buf * 16384;
    short8 bf[4][2];
#pragma unroll
    for (int n = 0; n < 4; ++n) {
      bf[n][0] = *(const short8*)(bufB + (wn4 + n) * 1024 + loe);
      bf[n][1] = *(const short8*)(bufB + (wn4 + n) * 1024 + 512 + loe);
    }
    // ---- phase 0 (m0,m1)
    {
      short8 af[2][2];
#pragma unroll
      for (int m = 0; m < 2; ++m) {
        af[m][0] = *(const short8*)(bufA + (wm8 + m) * 1024 + loe);
        af[m][1] = *(const short8*)(bufA + (wm8 + m) * 1024 + 512 + loe);
      }
      if (pre) { ISSUE_B(0, nb, nk); ISSUE_B(1, nb, nk); }
      __builtin_amdgcn_s_setprio(1);
#pragma unroll
      for (int m = 0; m < 2; ++m)
#pragma unroll
        for (int n = 0; n < 4; ++n) {
          acc[m][n] = mfma_bf16(af[m][0], bf[n][0], acc[m][n]);
          acc[m][n] = mfma_bf16(af[m][1], bf[n][1], acc[m][n]);
        }
      __builtin_amdgcn_s_setprio(0);
    }
    // ---- phase 1 (m2,m3)
    {
      short8 af[2][2];
#pragma unroll
      for (int m = 0; m < 2; ++m) {
        af[m][0] = *(const short8*)(bufA + (wm8 + 2 + m) * 1024 + loe);
        af[m][1] = *(const short8*)(bufA + (wm8 + 2 + m) * 1024 + 512 + loe);
      }
      if (pre) { ISSUE_B(2, nb, nk); ISSUE_B(3, nb, nk); }
      __builtin_amdgcn_s_setprio(1);
#pragma unroll
      for (int m = 0; m < 2; ++m)
#pragma unroll
        for (int n = 0; n < 4; ++n) {
          acc[2 + m][n] = mfma_bf16(af[m][0], bf[n][0], acc[2 + m][n]);
          acc[2 + m][n] = mfma_bf16(af[m][1], bf[n][1], acc[2 + m][n]);
        }
      __builtin_amdgcn_s_setprio(0);
    }
    // ---- mid-tile: A of current tile must fully land (A-half-2 used next)
    if (pre) {
      asm volatile("s_waitcnt vmcnt(4)" ::: "memory");
    } else {
      asm volatile("s_waitcnt vmcnt(0)" ::: "memory");
    }
    __builtin_amdgcn_s_barrier();
    asm volatile("" ::: "memory");
    // ---- phase 2 (m4,m5)
    {
      short8 af[2][2];
#pragma unroll
      for (int m = 0; m < 2; ++m) {
        af[m][0] = *(const short8*)(bufA + (wm8 + 4 + m) * 1024 + loe);
        af[m][1] = *(const short8*)(bufA + (wm8 + 4 + m) * 1024 + 512 + loe);
      }
      if (pre) { ISSUE_A(0, nb, nk); ISSUE_A(1, nb, nk); }
      __builtin_amdgcn_s_setprio(1);
#pragma unroll
      for (int m = 0; m < 2; ++m)
#pragma unroll
        for (int n = 0; n < 4; ++n) {
          acc[4 + m][n] = mfma_bf16(af[m][0], bf[n][0], acc[4 + m][n]);
          acc[4 + m][n] = mfma_bf16(af[m][1], bf[n][1], acc[4 + m][n]);
        }
      __builtin_amdgcn_s_setprio(0);
    }
    // ---- phase 3 (m6,m7)
    {
      short8 af[2][2];
#pragma unroll
      for (int m = 0; m < 2; ++m) {
        af[m][0] = *(const short8*)(bufA + (wm8 + 6 + m) * 1024 + loe);
        af[m][1] = *(const short8*)(bufA + (wm8 + 6 + m) * 1024 + 512 + loe);
      }
      if (pre) { ISSUE_A(2, nb, nk); ISSUE_A(3, nb, nk); }
      __builtin_amdgcn_s_setprio(1);
#pragma unroll
      for (int m = 0; m < 2; ++m)
#pragma unroll
        for (int n = 0; n < 4; ++n) {
          acc[6 + m][n] = mfma_bf16(af[m][0], bf[n][0], acc[6 + m][n]);
          acc[6 + m][n] = mfma_bf16(af[m][1], bf[n][1], acc[6 + m][n]);
        }
      __builtin_amdgcn_s_setprio(0);
    }
    buf ^= 1;
  }
  asm volatile("s_nop 7\n\ts_nop 7\n\ts_nop 7" ::);  // MFMA->VALU hazard guard
#undef ISSUE_A
#undef ISSUE_B
}

// ---- fp32 -> bf16 convert (vectorized), exact launch: grid*256 == n4
__global__ __launch_bounds__(256) void cvt_kernel(const float* __restrict__ in,
                                                  u16* __restrict__ out, int n4) {
  int i = blockIdx.x * 256 + threadIdx.x;
  if (i >= n4) return;
  float4 v = ((const float4*)in)[i];
  u16x4 o;
  o[0] = f2bf(v.x); o[1] = f2bf(v.y); o[2] = f2bf(v.z); o[3] = f2bf(v.w);
  ((u16x4*)out)[i] = o;
}

// ---- merged projections (flat grid 768, XCD-swizzled, uniform NT=16):
// wg<512: q/k: m0=(wg>>3)*256 rows, z=(wg>>2)&1, n0=(wg&3)*256 cols.
// wg>=512: vT[b][d][k] = Wv @ emb^T: r=wg-512, m0=(r&3)*256 (d), n0=(r>>2)*256 (rows).
__global__ __launch_bounds__(512) void proj256_kernel(const u16* __restrict__ emb16,
                                                      const u16* __restrict__ Bq,
                                                      const u16* __restrict__ Bk,
                                                      const u16* __restrict__ Bv,
                                                      const float* __restrict__ bq,
                                                      const float* __restrict__ bk,
                                                      const float* __restrict__ bv,
                                                      u16* __restrict__ q16,
                                                      u16* __restrict__ k16,
                                                      u16* __restrict__ vT) {
  __shared__ __align__(16) u16 sm[65536];  // 128KB
  const int wg = xcd_swz(blockIdx.x, 768);
  const int lane = threadIdx.x & 63, wid = threadIdx.x >> 6;
  f32x4 acc[8][4] = {};
  if (wg < 512) {
    const int m0 = (wg >> 3) * 256;
    const int z = (wg >> 2) & 1;
    const int n0 = (wg & 3) * 256;
    gemm256_core(emb16 + (size_t)m0 * 1024, (z ? Bk : Bq) + (size_t)n0 * 1024,
                 16, 1024, 1024, sm, acc);
    const int rb = m0 + ((wid >> 2) << 7) + ((lane >> 4) << 2);
    const int cb = n0 + ((wid & 3) << 6) + (lane & 15);
    const float* bias = z ? bk : bq;
    u16* dst = z ? k16 : q16;
#pragma unroll
    for (int m = 0; m < 8; ++m)
#pragma unroll
      for (int n = 0; n < 4; ++n)
#pragma unroll
        for (int j = 0; j < 4; ++j) {
          int row = rb + m * 16 + j;
          int col = cb + n * 16;
          dst[(size_t)row * DIM + col] = f2bf(acc[m][n][j] + bias[col]);
        }
  } else {
    const int r = wg - 512;
    const int m0 = (r & 3) * 256;   // over DIM (Wv bands, L2-resident)
    const int n0 = (r >> 2) * 256;  // over MROWS (emb streamed once)
    gemm256_core(Bv + (size_t)m0 * 1024, emb16 + (size_t)n0 * 1024,
                 16, 1024, 1024, sm, acc);
    const int rb = m0 + ((wid >> 2) << 7) + ((lane >> 4) << 2);
    const int cb = n0 + ((wid & 3) << 6) + (lane & 15);
#pragma unroll
    for (int m = 0; m < 8; ++m)
#pragma unroll
      for (int n = 0; n < 4; ++n)
#pragma unroll
        for (int j = 0; j < 4; ++j) {
          int d = rb + m * 16 + j;     // 0..1023
          int kg = cb + n * 16;        // 0..16383
          int bi = kg >> 11, s = kg & 2047;
          vT[((size_t)bi << 21) + ((size_t)d << 11) + s] = f2bf(acc[m][n][j] + bv[d]);
        }
  }
}

// ---- scores: scF = (q.k^T + mask) / 32  (fp32) ; flat grid 512, one batch/XCD
__global__ __launch_bounds__(512) void scores256_kernel(const u16* __restrict__ q16,
                                                        const u16* __restrict__ k16,
                                                        const float* __restrict__ mask,
                                                        float* __restrict__ scF) {
  __shared__ __align__(16) u16 sm[65536];
  const int wg = xcd_swz(blockIdx.x, 512);
  const int b = wg >> 6;
  const int m0 = ((wg >> 3) & 7) * 256;
  const int n0 = (wg & 7) * 256;
  f32x4 acc[8][4] = {};
  gemm256_core(q16 + ((size_t)b * SEQ + m0) * DIM, k16 + ((size_t)b * SEQ + n0) * DIM,
               16, DIM, DIM, sm, acc);
  const int lane = threadIdx.x & 63, wid = threadIdx.x >> 6;
  const int rb = m0 + ((wid >> 2) << 7) + ((lane >> 4) << 2);
  const int cb = n0 + ((wid & 3) << 6) + (lane & 15);
#pragma unroll
  for (int m = 0; m < 8; ++m)
#pragma unroll
    for (int n = 0; n < 4; ++n)
#pragma unroll
      for (int j = 0; j < 4; ++j) {
        size_t idx = ((size_t)b * SEQ + rb + m * 16 + j) * SEQ + (cb + n * 16);
        scF[idx] = (acc[m][n][j] + mask[idx]) * 0.03125f;
      }
}

// ---- PV: out = probs @ v^T ; probs bf16 at row stride 4096 u16 inside scF
__global__ __launch_bounds__(512) void pv256_kernel(const u16* __restrict__ pr,
                                                    const u16* __restrict__ vt,
                                                    float* __restrict__ out) {
  __shared__ __align__(16) u16 sm[65536];
  const int wg = xcd_swz(blockIdx.x, 256);
  const int b = wg >> 5;
  const int m0 = ((wg >> 2) & 7) * 256;
  const int n0 = (wg & 3) * 256;
  f32x4 acc[8][4] = {};
  gemm256_core(pr + ((size_t)b * SEQ + m0) * (2 * SEQ), vt + ((size_t)b * DIM + n0) * SEQ,
               32, 2 * SEQ, SEQ, sm, acc);
  const int lane = threadIdx.x & 63, wid = threadIdx.x >> 6;
  const int rb = m0 + ((wid >> 2) << 7) + ((lane >> 4) << 2);
  const int cb = n0 + ((wid & 3) << 6) + (lane & 15);
#pragma unroll
  for (int m = 0; m < 8; ++m)
#pragma unroll
    for (int n = 0; n < 4; ++n)
#pragma unroll
      for (int j = 0; j < 4; ++j)
        out[((size_t)b * SEQ + rb + m * 16 + j) * DIM + (cb + n * 16)] = acc[m][n][j];
}

// ---- fp32 row softmax; writes bf16 probs in place into row-local first half
__global__ __launch_bounds__(256) void softmax_kernel(float* __restrict__ scF) {
  __shared__ float red[8];
  const size_t row = blockIdx.x;
  float* rowp = scF + row * SEQ;
  const int tid = threadIdx.x;
  float4 v0 = ((const float4*)rowp)[2 * tid];
  float4 v1 = ((const float4*)rowp)[2 * tid + 1];
  float f[8] = {v0.x, v0.y, v0.z, v0.w, v1.x, v1.y, v1.z, v1.w};
  float mx = f[0];
#pragma unroll
  for (int j = 1; j < 8; ++j) mx = fmaxf(mx, f[j]);
#pragma unroll
  for (int off = 1; off < 64; off <<= 1) mx = fmaxf(mx, __shfl_xor(mx, off));
  const int wid = tid >> 6, lane = tid & 63;
  if (lane == 0) red[wid] = mx;
  __syncthreads();
  mx = fmaxf(fmaxf(red[0], red[1]), fmaxf(red[2], red[3]));
  float e[8];
  float s = 0.f;
#pragma unroll
  for (int j = 0; j < 8; ++j) {
    e[j] = __expf(f[j] - mx);
    s += e[j];
  }
#pragma unroll
  for (int off = 1; off < 64; off <<= 1) s += __shfl_xor(s, off);
  if (lane == 0) red[4 + wid] = s;
  __syncthreads();
  s = (red[4] + red[5]) + (red[6] + red[7]);
  const float inv = 1.f / s;
  short8 o;
#pragma unroll
  for (int j = 0; j < 8; ++j) o[j] = (short)f2bf(e[j] * inv);
  *(short8*)((u16*)rowp + tid * 8) = o;
}

extern "C" void kernel_launch(void* const* d_in, const int* in_sizes, int n_in,
                              void* d_out, int out_size, void* d_ws, size_t ws_size,
                              hipStream_t stream) {
  const float* emb  = (const float*)d_in[0];
  const float* mask = (const float*)d_in[1];
  const float* Wq   = (const float*)d_in[2];
  const float* bq   = (const float*)d_in[3];
  const float* Wk   = (const float*)d_in[4];
  const float* bk   = (const float*)d_in[5];
  const float* Wv   = (const float*)d_in[6];
  const float* bv   = (const float*)d_in[7];
  float* out = (float*)d_out;

  const size_t M1 = 1024 * 1024;
  float* scF  = (float*)d_ws;                 // 32M fp32 (128MB)
  u16* emb16 = (u16*)d_ws + 64 * M1;          // 16M u16
  u16* Bq  = emb16 + 16 * M1;                 // 1M
  u16* Bk  = Bq + 1 * M1;                     // 1M
  u16* Bv  = Bk + 1 * M1;                     // 1M
  u16* q16 = Bv + 1 * M1;                     // 16M
  u16* k16 = q16 + 16 * M1;                   // 16M
  u16* vT  = k16 + 16 * M1;                   // 16M  (ends at 131M u16 = 262MB)

  cvt_kernel<<<16384, 256, 0, stream>>>(emb, emb16, (int)(4 * M1));
  cvt_kernel<<<1024, 256, 0, stream>>>(Wq, Bq, (int)(M1 / 4));
  cvt_kernel<<<1024, 256, 0, stream>>>(Wk, Bk, (int)(M1 / 4));
  cvt_kernel<<<1024, 256, 0, stream>>>(Wv, Bv, (int)(M1 / 4));

  proj256_kernel<<<768, 512, 0, stream>>>(emb16, Bq, Bk, Bv, bq, bk, bv, q16, k16, vT);

  scores256_kernel<<<512, 512, 0, stream>>>(q16, k16, mask, scF);
  softmax_kernel<<<MROWS, 256, 0, stream>>>(scF);
  pv256_kernel<<<256, 512, 0, stream>>>((const u16*)scF, vT, out);
}

// Round 7
// 305.804 us; speedup vs baseline: 1.6926x; 1.0662x over previous
//
#include <hip/hip_runtime.h>

// SelfAttention: B=8, S=2048, D=1024, fp32 in/out — ALL-FP16 MFMA pipeline.
// GEMMs on a 256x256-tile, 8-wave, BK=64 double-buffered MFMA core with
// swizzled LDS (pre-swizzled global staging), counted vmcnt, setprio,
// XCD-chunked block swizzle. Merged projection kernel (uniform NT=16):
// q,k = emb@W^T; vT = Wv@emb^T (transpose free via operand swap).
// scores: raw s/32 stored fp16 (no mask, tiny epilogue); softmax adds mask/32,
// fp32 math, writes fp16 probs in place; PV fp16 MFMA, fp32 out.
// d_ws (u16): scH[32M] | emb16[16M] | Bq[1M] Bk[1M] Bv[1M] | q16[16M] k16[16M]
//   vT[16M] = 83M u16 = 166MB.

#define B_SZ 8
#define SEQ  2048
#define DIM  1024
#define MROWS (B_SZ * SEQ)  // 16384

typedef unsigned short u16;
typedef short short8 __attribute__((ext_vector_type(8)));
typedef unsigned short u16x4 __attribute__((ext_vector_type(4)));
typedef float f32x4 __attribute__((ext_vector_type(4)));

__device__ __forceinline__ u16 f2h(float x) {
  _Float16 h = (_Float16)x;  // v_cvt_f16_f32, RNE
  union { _Float16 f; u16 u; } c; c.f = h; return c.u;
}
__device__ __forceinline__ float h2f(u16 u) {
  union { _Float16 f; u16 u; } c; c.u = u; return (float)c.f;
}

// XCD-chunked bijective swizzle (nwg % 8 == 0)
__device__ __forceinline__ int xcd_swz(int x, int nwg) {
  return (x & 7) * (nwg >> 3) + (x >> 3);
}

__device__ __forceinline__ void gload_lds16(const u16* g, u16* l) {
  __builtin_amdgcn_global_load_lds(
      (__attribute__((address_space(1))) void*)(g),
      (__attribute__((address_space(3))) void*)(l), 16, 0, 0);
}

__device__ __forceinline__ f32x4 mfma_f16(short8 a, short8 b, f32x4 c) {
  asm("v_mfma_f32_16x16x32_f16 %0, %1, %2, %0" : "+v"(c) : "v"(a), "v"(b));
  return c;
}

// ================= 256x256 8-wave GEMM core (fp16 elements) =================
// Identical structure to prior rounds; element type is opaque 16-bit.
__device__ __forceinline__ void gemm256_core(const u16* __restrict__ Ag,
                                             const u16* __restrict__ Bg,
                                             int NT, size_t lda, size_t ldb,
                                             u16* sm, f32x4 (&acc)[8][4]) {
  const int tid = threadIdx.x;
  const int lane = tid & 63;
  const int wid = tid >> 6;   // 0..7
  const int wm = wid >> 2;    // 0..1
  const int wn = wid & 3;     // 0..3
  const int wm8 = wm << 3;
  const int wn4 = wn << 2;

  u16* sA = sm;            // [2][16384] u16 (32KB per buf)
  u16* sB = sm + 32768;

  const int bb = (lane << 4) ^ (((lane >> 5) & 1) << 5);
  const int rins = bb >> 6;
  const int cins = (bb & 63) >> 1;
  const int s0 = wid, s1 = 8 + wid, s2 = 16 + wid, s3 = 24 + wid;
  const size_t aoff0 = (size_t)((s0 >> 1) * 16 + rins) * lda + ((s0 & 1) * 32 + cins);
  const size_t aoff1 = (size_t)((s1 >> 1) * 16 + rins) * lda + ((s1 & 1) * 32 + cins);
  const size_t aoff2 = (size_t)((s2 >> 1) * 16 + rins) * lda + ((s2 & 1) * 32 + cins);
  const size_t aoff3 = (size_t)((s3 >> 1) * 16 + rins) * lda + ((s3 & 1) * 32 + cins);
  const size_t boff0 = (size_t)((s0 >> 1) * 16 + rins) * ldb + ((s0 & 1) * 32 + cins);
  const size_t boff1 = (size_t)((s1 >> 1) * 16 + rins) * ldb + ((s1 & 1) * 32 + cins);
  const size_t boff2 = (size_t)((s2 >> 1) * 16 + rins) * ldb + ((s2 & 1) * 32 + cins);
  const size_t boff3 = (size_t)((s3 >> 1) * 16 + rins) * ldb + ((s3 & 1) * 32 + cins);
  const int wid512 = wid << 9;

  const int lof = ((lane & 15) << 6) + ((lane >> 4) << 4);
  const int loe = (lof ^ (((lane >> 3) & 1) << 5)) >> 1;

#define ISSUE_A(j, nb, kt) \
  gload_lds16(Ag + aoff##j + (size_t)(kt) * 64, sA + (nb) * 16384 + (j) * 4096 + wid512)
#define ISSUE_B(j, nb, kt) \
  gload_lds16(Bg + boff##j + (size_t)(kt) * 64, sB + (nb) * 16384 + (j) * 4096 + wid512)

  ISSUE_B(0, 0, 0); ISSUE_B(1, 0, 0); ISSUE_B(2, 0, 0); ISSUE_B(3, 0, 0);
  ISSUE_A(0, 0, 0); ISSUE_A(1, 0, 0); ISSUE_A(2, 0, 0); ISSUE_A(3, 0, 0);

  int buf = 0;
  for (int kt = 0; kt < NT; ++kt) {
    const int nk = kt + 1;
    const bool pre = nk < NT;
    const int nb = buf ^ 1;
    asm volatile("s_waitcnt vmcnt(1)" ::: "memory");
    __builtin_amdgcn_s_barrier();
    asm volatile("" ::: "memory");
    const u16* bufA = sA + buf * 16384;
    const u16* bufB = sB + buf * 16384;
    short8 bf[4][2];
#pragma unroll
    for (int n = 0; n < 4; ++n) {
      bf[n][0] = *(const short8*)(bufB + (wn4 + n) * 1024 + loe);
      bf[n][1] = *(const short8*)(bufB + (wn4 + n) * 1024 + 512 + loe);
    }
    // ---- phase 0 (m0,m1)
    {
      short8 af[2][2];
#pragma unroll
      for (int m = 0; m < 2; ++m) {
        af[m][0] = *(const short8*)(bufA + (wm8 + m) * 1024 + loe);
        af[m][1] = *(const short8*)(bufA + (wm8 + m) * 1024 + 512 + loe);
      }
      if (pre) { ISSUE_B(0, nb, nk); ISSUE_B(1, nb, nk); }
      __builtin_amdgcn_s_setprio(1);
#pragma unroll
      for (int m = 0; m < 2; ++m)
#pragma unroll
        for (int n = 0; n < 4; ++n) {
          acc[m][n] = mfma_f16(af[m][0], bf[n][0], acc[m][n]);
          acc[m][n] = mfma_f16(af[m][1], bf[n][1], acc[m][n]);
        }
      __builtin_amdgcn_s_setprio(0);
    }
    // ---- phase 1 (m2,m3)
    {
      short8 af[2][2];
#pragma unroll
      for (int m = 0; m < 2; ++m) {
        af[m][0] = *(const short8*)(bufA + (wm8 + 2 + m) * 1024 + loe);
        af[m][1] = *(const short8*)(bufA + (wm8 + 2 + m) * 1024 + 512 + loe);
      }
      if (pre) { ISSUE_B(2, nb, nk); ISSUE_B(3, nb, nk); }
      __builtin_amdgcn_s_setprio(1);
#pragma unroll
      for (int m = 0; m < 2; ++m)
#pragma unroll
        for (int n = 0; n < 4; ++n) {
          acc[2 + m][n] = mfma_f16(af[m][0], bf[n][0], acc[2 + m][n]);
          acc[2 + m][n] = mfma_f16(af[m][1], bf[n][1], acc[2 + m][n]);
        }
      __builtin_amdgcn_s_setprio(0);
    }
    if (pre) {
      asm volatile("s_waitcnt vmcnt(4)" ::: "memory");
    } else {
      asm volatile("s_waitcnt vmcnt(0)" ::: "memory");
    }
    __builtin_amdgcn_s_barrier();
    asm volatile("" ::: "memory");
    // ---- phase 2 (m4,m5)
    {
      short8 af[2][2];
#pragma unroll
      for (int m = 0; m < 2; ++m) {
        af[m][0] = *(const short8*)(bufA + (wm8 + 4 + m) * 1024 + loe);
        af[m][1] = *(const short8*)(bufA + (wm8 + 4 + m) * 1024 + 512 + loe);
      }
      if (pre) { ISSUE_A(0, nb, nk); ISSUE_A(1, nb, nk); }
      __builtin_amdgcn_s_setprio(1);
#pragma unroll
      for (int m = 0; m < 2; ++m)
#pragma unroll
        for (int n = 0; n < 4; ++n) {
          acc[4 + m][n] = mfma_f16(af[m][0], bf[n][0], acc[4 + m][n]);
          acc[4 + m][n] = mfma_f16(af[m][1], bf[n][1], acc[4 + m][n]);
        }
      __builtin_amdgcn_s_setprio(0);
    }
    // ---- phase 3 (m6,m7)
    {
      short8 af[2][2];
#pragma unroll
      for (int m = 0; m < 2; ++m) {
        af[m][0] = *(const short8*)(bufA + (wm8 + 6 + m) * 1024 + loe);
        af[m][1] = *(const short8*)(bufA + (wm8 + 6 + m) * 1024 + 512 + loe);
      }
      if (pre) { ISSUE_A(2, nb, nk); ISSUE_A(3, nb, nk); }
      __builtin_amdgcn_s_setprio(1);
#pragma unroll
      for (int m = 0; m < 2; ++m)
#pragma unroll
        for (int n = 0; n < 4; ++n) {
          acc[6 + m][n] = mfma_f16(af[m][0], bf[n][0], acc[6 + m][n]);
          acc[6 + m][n] = mfma_f16(af[m][1], bf[n][1], acc[6 + m][n]);
        }
      __builtin_amdgcn_s_setprio(0);
    }
    buf ^= 1;
  }
  asm volatile("s_nop 7\n\ts_nop 7\n\ts_nop 7" ::);  // MFMA->VALU hazard guard
#undef ISSUE_A
#undef ISSUE_B
}

// ---- fp32 -> fp16 convert (vectorized)
__global__ __launch_bounds__(256) void cvt_kernel(const float* __restrict__ in,
                                                  u16* __restrict__ out, int n4) {
  int i = blockIdx.x * 256 + threadIdx.x;
  if (i >= n4) return;
  float4 v = ((const float4*)in)[i];
  u16x4 o;
  o[0] = f2h(v.x); o[1] = f2h(v.y); o[2] = f2h(v.z); o[3] = f2h(v.w);
  ((u16x4*)out)[i] = o;
}

// ---- merged projections (flat grid 768, XCD-swizzled, uniform NT=16)
__global__ __launch_bounds__(512) void proj256_kernel(const u16* __restrict__ emb16,
                                                      const u16* __restrict__ Bq,
                                                      const u16* __restrict__ Bk,
                                                      const u16* __restrict__ Bv,
                                                      const float* __restrict__ bq,
                                                      const float* __restrict__ bk,
                                                      const float* __restrict__ bv,
                                                      u16* __restrict__ q16,
                                                      u16* __restrict__ k16,
                                                      u16* __restrict__ vT) {
  __shared__ __align__(16) u16 sm[65536];  // 128KB
  const int wg = xcd_swz(blockIdx.x, 768);
  const int lane = threadIdx.x & 63, wid = threadIdx.x >> 6;
  f32x4 acc[8][4] = {};
  if (wg < 512) {
    const int m0 = (wg >> 3) * 256;
    const int z = (wg >> 2) & 1;
    const int n0 = (wg & 3) * 256;
    gemm256_core(emb16 + (size_t)m0 * 1024, (z ? Bk : Bq) + (size_t)n0 * 1024,
                 16, 1024, 1024, sm, acc);
    const int rb = m0 + ((wid >> 2) << 7) + ((lane >> 4) << 2);
    const int cb = n0 + ((wid & 3) << 6) + (lane & 15);
    const float* bias = z ? bk : bq;
    u16* dst = z ? k16 : q16;
#pragma unroll
    for (int m = 0; m < 8; ++m)
#pragma unroll
      for (int n = 0; n < 4; ++n)
#pragma unroll
        for (int j = 0; j < 4; ++j) {
          int row = rb + m * 16 + j;
          int col = cb + n * 16;
          dst[(size_t)row * DIM + col] = f2h(acc[m][n][j] + bias[col]);
        }
  } else {
    const int r = wg - 512;
    const int m0 = (r & 3) * 256;   // over DIM (Wv bands, L2-resident)
    const int n0 = (r >> 2) * 256;  // over MROWS (emb streamed once)
    gemm256_core(Bv + (size_t)m0 * 1024, emb16 + (size_t)n0 * 1024,
                 16, 1024, 1024, sm, acc);
    const int rb = m0 + ((wid >> 2) << 7) + ((lane >> 4) << 2);
    const int cb = n0 + ((wid & 3) << 6) + (lane & 15);
#pragma unroll
    for (int m = 0; m < 8; ++m)
#pragma unroll
      for (int n = 0; n < 4; ++n)
#pragma unroll
        for (int j = 0; j < 4; ++j) {
          int d = rb + m * 16 + j;     // 0..1023
          int kg = cb + n * 16;        // 0..16383
          int bi = kg >> 11, s = kg & 2047;
          vT[((size_t)bi << 21) + ((size_t)d << 11) + s] = f2h(acc[m][n][j] + bv[d]);
        }
  }
}

// ---- scores: scH = fp16( q.k^T / 32 )  (no mask here; tiny epilogue)
__global__ __launch_bounds__(512) void scores256_kernel(const u16* __restrict__ q16,
                                                        const u16* __restrict__ k16,
                                                        u16* __restrict__ scH) {
  __shared__ __align__(16) u16 sm[65536];
  const int wg = xcd_swz(blockIdx.x, 512);
  const int b = wg >> 6;
  const int m0 = ((wg >> 3) & 7) * 256;
  const int n0 = (wg & 7) * 256;
  f32x4 acc[8][4] = {};
  gemm256_core(q16 + ((size_t)b * SEQ + m0) * DIM, k16 + ((size_t)b * SEQ + n0) * DIM,
               16, DIM, DIM, sm, acc);
  const int lane = threadIdx.x & 63, wid = threadIdx.x >> 6;
  const int rb = m0 + ((wid >> 2) << 7) + ((lane >> 4) << 2);
  const int cb = n0 + ((wid & 3) << 6) + (lane & 15);
#pragma unroll
  for (int m = 0; m < 8; ++m)
#pragma unroll
    for (int n = 0; n < 4; ++n)
#pragma unroll
      for (int j = 0; j < 4; ++j) {
        size_t idx = ((size_t)b * SEQ + rb + m * 16 + j) * SEQ + (cb + n * 16);
        scH[idx] = f2h(acc[m][n][j] * 0.03125f);
      }
}

// ---- softmax: f = scH + mask/32 (fp32 math), probs fp16 written in place
__global__ __launch_bounds__(256) void softmax_kernel(u16* __restrict__ scH,
                                                      const float* __restrict__ mask) {
  __shared__ float red[8];
  const size_t row = blockIdx.x;
  u16* rowp = scH + row * SEQ;
  const float* mrow = mask + row * SEQ;
  const int tid = threadIdx.x;
  short8 raw = *(const short8*)(rowp + tid * 8);
  float4 m0 = ((const float4*)mrow)[2 * tid];
  float4 m1 = ((const float4*)mrow)[2 * tid + 1];
  float mk[8] = {m0.x, m0.y, m0.z, m0.w, m1.x, m1.y, m1.z, m1.w};
  float f[8];
#pragma unroll
  for (int j = 0; j < 8; ++j) f[j] = h2f((u16)raw[j]) + mk[j] * 0.03125f;
  float mx = f[0];
#pragma unroll
  for (int j = 1; j < 8; ++j) mx = fmaxf(mx, f[j]);
#pragma unroll
  for (int off = 1; off < 64; off <<= 1) mx = fmaxf(mx, __shfl_xor(mx, off));
  const int wid = tid >> 6, lane = tid & 63;
  if (lane == 0) red[wid] = mx;
  __syncthreads();
  mx = fmaxf(fmaxf(red[0], red[1]), fmaxf(red[2], red[3]));
  float e[8];
  float s = 0.f;
#pragma unroll
  for (int j = 0; j < 8; ++j) {
    e[j] = __expf(f[j] - mx);
    s += e[j];
  }
#pragma unroll
  for (int off = 1; off < 64; off <<= 1) s += __shfl_xor(s, off);
  if (lane == 0) red[4 + wid] = s;
  __syncthreads();
  s = (red[4] + red[5]) + (red[6] + red[7]);
  const float inv = 1.f / s;
  short8 o;
#pragma unroll
  for (int j = 0; j < 8; ++j) o[j] = (short)f2h(e[j] * inv);
  *(short8*)(rowp + tid * 8) = o;
}

// ---- PV: out = probs @ v^T  (probs fp16, full rows stride 2048)
__global__ __launch_bounds__(512) void pv256_kernel(const u16* __restrict__ pr,
                                                    const u16* __restrict__ vt,
                                                    float* __restrict__ out) {
  __shared__ __align__(16) u16 sm[65536];
  const int wg = xcd_swz(blockIdx.x, 256);
  const int b = wg >> 5;
  const int m0 = ((wg >> 2) & 7) * 256;
  const int n0 = (wg & 3) * 256;
  f32x4 acc[8][4] = {};
  gemm256_core(pr + ((size_t)b * SEQ + m0) * SEQ, vt + ((size_t)b * DIM + n0) * SEQ,
               32, SEQ, SEQ, sm, acc);
  const int lane = threadIdx.x & 63, wid = threadIdx.x >> 6;
  const int rb = m0 + ((wid >> 2) << 7) + ((lane >> 4) << 2);
  const int cb = n0 + ((wid & 3) << 6) + (lane & 15);
#pragma unroll
  for (int m = 0; m < 8; ++m)
#pragma unroll
    for (int n = 0; n < 4; ++n)
#pragma unroll
      for (int j = 0; j < 4; ++j)
        out[((size_t)b * SEQ + rb + m * 16 + j) * DIM + (cb + n * 16)] = acc[m][n][j];
}

extern "C" void kernel_launch(void* const* d_in, const int* in_sizes, int n_in,
                              void* d_out, int out_size, void* d_ws, size_t ws_size,
                              hipStream_t stream) {
  const float* emb  = (const float*)d_in[0];
  const float* mask = (const float*)d_in[1];
  const float* Wq   = (const float*)d_in[2];
  const float* bq   = (const float*)d_in[3];
  const float* Wk   = (const float*)d_in[4];
  const float* bk   = (const float*)d_in[5];
  const float* Wv   = (const float*)d_in[6];
  const float* bv   = (const float*)d_in[7];
  float* out = (float*)d_out;

  const size_t M1 = 1024 * 1024;
  u16* scH   = (u16*)d_ws;                    // 32M u16 (64MB), fp16 logits->probs
  u16* emb16 = scH + 32 * M1;                 // 16M
  u16* Bq  = emb16 + 16 * M1;                 // 1M
  u16* Bk  = Bq + 1 * M1;                     // 1M
  u16* Bv  = Bk + 1 * M1;                     // 1M
  u16* q16 = Bv + 1 * M1;                     // 16M
  u16* k16 = q16 + 16 * M1;                   // 16M
  u16* vT  = k16 + 16 * M1;                   // 16M  (83M u16 = 166MB)

  cvt_kernel<<<16384, 256, 0, stream>>>(emb, emb16, (int)(4 * M1));
  cvt_kernel<<<1024, 256, 0, stream>>>(Wq, Bq, (int)(M1 / 4));
  cvt_kernel<<<1024, 256, 0, stream>>>(Wk, Bk, (int)(M1 / 4));
  cvt_kernel<<<1024, 256, 0, stream>>>(Wv, Bv, (int)(M1 / 4));

  proj256_kernel<<<768, 512, 0, stream>>>(emb16, Bq, Bk, Bv, bq, bk, bv, q16, k16, vT);

  scores256_kernel<<<512, 512, 0, stream>>>(q16, k16, scH);
  softmax_kernel<<<MROWS, 256, 0, stream>>>(scH, mask);
  pv256_kernel<<<256, 512, 0, stream>>>((const u16*)scH, vT, out);
}